// Round 1
// baseline (1494.024 us; speedup 1.0000x reference)
//
#include <hip/hip_runtime.h>

#define S_FEAT 16
#define D_FEAT 8
#define E_FEAT 4
#define EDGE_IN 52   // E_FEAT + 2*S_FEAT + 2*D_FEAT
#define HIDDEN 16    // 2*D_FEAT

// ---------------------------------------------------------------------------
// Per-edge MLP: e = [x_s[row], x_s[col], x_d[row], x_d[col], edge_attr[e]]
// h = relu(e @ W1.T + b1); s = h @ W2.T + b2; s /= ||s|| (0 if norm==0)
// Weights are wave-uniform -> compiler emits scalar loads (s_load) + v_fmac.
// ---------------------------------------------------------------------------
__device__ __forceinline__ void mlp_sij(
    const float* __restrict__ x_s, const float* __restrict__ x_d,
    const float* __restrict__ edge_attr,
    const float* __restrict__ W1, const float* __restrict__ b1,
    const float* __restrict__ W2, const float* __restrict__ b2,
    int row, int col, int e, float s[D_FEAT])
{
    float in[EDGE_IN];
    {
        const float4* p = (const float4*)(x_s + (size_t)row * S_FEAT);
#pragma unroll
        for (int q = 0; q < 4; ++q) {
            float4 v = p[q];
            in[q * 4 + 0] = v.x; in[q * 4 + 1] = v.y;
            in[q * 4 + 2] = v.z; in[q * 4 + 3] = v.w;
        }
    }
    {
        const float4* p = (const float4*)(x_s + (size_t)col * S_FEAT);
#pragma unroll
        for (int q = 0; q < 4; ++q) {
            float4 v = p[q];
            in[16 + q * 4 + 0] = v.x; in[16 + q * 4 + 1] = v.y;
            in[16 + q * 4 + 2] = v.z; in[16 + q * 4 + 3] = v.w;
        }
    }
    {
        const float4* p = (const float4*)(x_d + (size_t)row * D_FEAT);
#pragma unroll
        for (int q = 0; q < 2; ++q) {
            float4 v = p[q];
            in[32 + q * 4 + 0] = v.x; in[32 + q * 4 + 1] = v.y;
            in[32 + q * 4 + 2] = v.z; in[32 + q * 4 + 3] = v.w;
        }
    }
    {
        const float4* p = (const float4*)(x_d + (size_t)col * D_FEAT);
#pragma unroll
        for (int q = 0; q < 2; ++q) {
            float4 v = p[q];
            in[40 + q * 4 + 0] = v.x; in[40 + q * 4 + 1] = v.y;
            in[40 + q * 4 + 2] = v.z; in[40 + q * 4 + 3] = v.w;
        }
    }
    {
        float4 v = *(const float4*)(edge_attr + (size_t)e * E_FEAT);
        in[48] = v.x; in[49] = v.y; in[50] = v.z; in[51] = v.w;
    }

    float h[HIDDEN];
#pragma unroll
    for (int i = 0; i < HIDDEN; ++i) {
        float acc = b1[i];
#pragma unroll
        for (int j = 0; j < EDGE_IN; ++j)
            acc = fmaf(in[j], W1[i * EDGE_IN + j], acc);
        h[i] = acc > 0.f ? acc : 0.f;
    }

    float nrm2 = 0.f;
#pragma unroll
    for (int i = 0; i < D_FEAT; ++i) {
        float acc = b2[i];
#pragma unroll
        for (int j = 0; j < HIDDEN; ++j)
            acc = fmaf(h[j], W2[i * HIDDEN + j], acc);
        s[i] = acc;
        nrm2 = fmaf(acc, acc, nrm2);
    }
    float nrm = sqrtf(nrm2);
    float inv = nrm > 0.f ? 1.f / nrm : 0.f;
#pragma unroll
    for (int i = 0; i < D_FEAT; ++i) s[i] *= inv;
}

// ---------------------------------------------------------------------------
// Kernel 1: s_ij for every edge -> ws (path A)
// ---------------------------------------------------------------------------
__global__ __launch_bounds__(256) void edge_mlp_kernel(
    const float* __restrict__ x_s, const float* __restrict__ x_d,
    const float* __restrict__ edge_attr,
    const float* __restrict__ W1, const float* __restrict__ b1,
    const float* __restrict__ W2, const float* __restrict__ b2,
    const int* __restrict__ ei, int E, float* __restrict__ s_out)
{
    int e = blockIdx.x * blockDim.x + threadIdx.x;
    if (e >= E) return;
    int row = ei[e], col = ei[E + e];
    float s[D_FEAT];
    mlp_sij(x_s, x_d, edge_attr, W1, b1, W2, b2, row, col, e, s);
    float4* o = (float4*)(s_out + (size_t)e * D_FEAT);
    o[0] = make_float4(s[0], s[1], s[2], s[3]);
    o[1] = make_float4(s[4], s[5], s[6], s[7]);
}

// ---------------------------------------------------------------------------
// Kernel 2: out = x_d @ Wf0.T ; zero the scatter accumulator
// ---------------------------------------------------------------------------
__global__ __launch_bounds__(256) void node_init_kernel(
    const float* __restrict__ x_d, const float* __restrict__ Wf0,
    float* __restrict__ out, float* __restrict__ scattered, int N)
{
    int n = blockIdx.x * blockDim.x + threadIdx.x;
    if (n >= N) return;
    float xd[D_FEAT];
    {
        const float4* p = (const float4*)(x_d + (size_t)n * D_FEAT);
        float4 a = p[0], b = p[1];
        xd[0] = a.x; xd[1] = a.y; xd[2] = a.z; xd[3] = a.w;
        xd[4] = b.x; xd[5] = b.y; xd[6] = b.z; xd[7] = b.w;
    }
    float o[D_FEAT];
#pragma unroll
    for (int i = 0; i < D_FEAT; ++i) {
        float acc = 0.f;
#pragma unroll
        for (int j = 0; j < D_FEAT; ++j)
            acc = fmaf(xd[j], Wf0[i * D_FEAT + j], acc);
        o[i] = acc;
    }
    float4* op = (float4*)(out + (size_t)n * D_FEAT);
    op[0] = make_float4(o[0], o[1], o[2], o[3]);
    op[1] = make_float4(o[4], o[5], o[6], o[7]);
    float4* sp = (float4*)(scattered + (size_t)n * D_FEAT);
    sp[0] = make_float4(0.f, 0.f, 0.f, 0.f);
    sp[1] = make_float4(0.f, 0.f, 0.f, 0.f);
}

// ---------------------------------------------------------------------------
// Kernel 3a (path A): per-edge masked gradient * s_ij -> atomic scatter by col
// ---------------------------------------------------------------------------
__global__ __launch_bounds__(256) void edge_step_cached_kernel(
    const float* __restrict__ out, const float* __restrict__ s_ij,
    const int* __restrict__ ei, int E, float* __restrict__ scattered)
{
    int e = blockIdx.x * blockDim.x + threadIdx.x;
    if (e >= E) return;
    int row = ei[e], col = ei[E + e];
    const float4* pr = (const float4*)(out + (size_t)row * D_FEAT);
    const float4* pc = (const float4*)(out + (size_t)col * D_FEAT);
    float4 r0 = pr[0], r1 = pr[1], c0 = pc[0], c1 = pc[1];
    float srow = r0.x + r0.y + r0.z + r0.w + r1.x + r1.y + r1.z + r1.w;
    float scol = c0.x + c0.y + c0.z + c0.w + c1.x + c1.y + c1.z + c1.w;
    if (srow == 0.f && scol == 0.f) return;  // edge_mask == 0
    const float4* ps = (const float4*)(s_ij + (size_t)e * D_FEAT);
    float4 s0 = ps[0], s1 = ps[1];
    float* dst = scattered + (size_t)col * D_FEAT;
    atomicAdd(dst + 0, (c0.x - r0.x) * s0.x);
    atomicAdd(dst + 1, (c0.y - r0.y) * s0.y);
    atomicAdd(dst + 2, (c0.z - r0.z) * s0.z);
    atomicAdd(dst + 3, (c0.w - r0.w) * s0.w);
    atomicAdd(dst + 4, (c1.x - r1.x) * s1.x);
    atomicAdd(dst + 5, (c1.y - r1.y) * s1.y);
    atomicAdd(dst + 6, (c1.z - r1.z) * s1.z);
    atomicAdd(dst + 7, (c1.w - r1.w) * s1.w);
}

// ---------------------------------------------------------------------------
// Kernel 3b (path B fallback, ws too small): recompute s_ij on the fly
// ---------------------------------------------------------------------------
__global__ __launch_bounds__(256) void edge_step_fused_kernel(
    const float* __restrict__ x_s, const float* __restrict__ x_d,
    const float* __restrict__ edge_attr,
    const float* __restrict__ W1, const float* __restrict__ b1,
    const float* __restrict__ W2, const float* __restrict__ b2,
    const float* __restrict__ out,
    const int* __restrict__ ei, int E, float* __restrict__ scattered)
{
    int e = blockIdx.x * blockDim.x + threadIdx.x;
    if (e >= E) return;
    int row = ei[e], col = ei[E + e];
    const float4* pr = (const float4*)(out + (size_t)row * D_FEAT);
    const float4* pc = (const float4*)(out + (size_t)col * D_FEAT);
    float4 r0 = pr[0], r1 = pr[1], c0 = pc[0], c1 = pc[1];
    float srow = r0.x + r0.y + r0.z + r0.w + r1.x + r1.y + r1.z + r1.w;
    float scol = c0.x + c0.y + c0.z + c0.w + c1.x + c1.y + c1.z + c1.w;
    if (srow == 0.f && scol == 0.f) return;
    float s[D_FEAT];
    mlp_sij(x_s, x_d, edge_attr, W1, b1, W2, b2, row, col, e, s);
    float* dst = scattered + (size_t)col * D_FEAT;
    atomicAdd(dst + 0, (c0.x - r0.x) * s[0]);
    atomicAdd(dst + 1, (c0.y - r0.y) * s[1]);
    atomicAdd(dst + 2, (c0.z - r0.z) * s[2]);
    atomicAdd(dst + 3, (c0.w - r0.w) * s[3]);
    atomicAdd(dst + 4, (c1.x - r1.x) * s[4]);
    atomicAdd(dst + 5, (c1.y - r1.y) * s[5]);
    atomicAdd(dst + 6, (c1.z - r1.z) * s[6]);
    atomicAdd(dst + 7, (c1.w - r1.w) * s[7]);
}

// ---------------------------------------------------------------------------
// Kernel 4: out += scattered @ Wf.T ; re-zero scattered for the next step
// ---------------------------------------------------------------------------
__global__ __launch_bounds__(256) void node_update_kernel(
    float* __restrict__ out, float* __restrict__ scattered,
    const float* __restrict__ Wf, int N)
{
    int n = blockIdx.x * blockDim.x + threadIdx.x;
    if (n >= N) return;
    float sc[D_FEAT];
    float4* sp = (float4*)(scattered + (size_t)n * D_FEAT);
    {
        float4 a = sp[0], b = sp[1];
        sc[0] = a.x; sc[1] = a.y; sc[2] = a.z; sc[3] = a.w;
        sc[4] = b.x; sc[5] = b.y; sc[6] = b.z; sc[7] = b.w;
    }
    sp[0] = make_float4(0.f, 0.f, 0.f, 0.f);
    sp[1] = make_float4(0.f, 0.f, 0.f, 0.f);
    float4* op = (float4*)(out + (size_t)n * D_FEAT);
    float4 o0 = op[0], o1 = op[1];
    float o[D_FEAT] = {o0.x, o0.y, o0.z, o0.w, o1.x, o1.y, o1.z, o1.w};
#pragma unroll
    for (int i = 0; i < D_FEAT; ++i) {
        float acc = 0.f;
#pragma unroll
        for (int j = 0; j < D_FEAT; ++j)
            acc = fmaf(sc[j], Wf[i * D_FEAT + j], acc);
        o[i] += acc;
    }
    op[0] = make_float4(o[0], o[1], o[2], o[3]);
    op[1] = make_float4(o[4], o[5], o[6], o[7]);
}

extern "C" void kernel_launch(void* const* d_in, const int* in_sizes, int n_in,
                              void* d_out, int out_size, void* d_ws, size_t ws_size,
                              hipStream_t stream) {
    const float* x_s       = (const float*)d_in[0];
    const float* x_d       = (const float*)d_in[1];
    const float* edge_attr = (const float*)d_in[2];
    const float* W1        = (const float*)d_in[3];
    const float* b1        = (const float*)d_in[4];
    const float* W2        = (const float*)d_in[5];
    const float* b2        = (const float*)d_in[6];
    const float* Wf[3]     = {(const float*)d_in[7], (const float*)d_in[8],
                              (const float*)d_in[9]};
    const int*   ei        = (const int*)d_in[10];

    const int N = in_sizes[1] / D_FEAT;
    const int E = in_sizes[10] / 2;

    float* out = (float*)d_out;

    const size_t sij_bytes = (size_t)E * D_FEAT * sizeof(float);
    const size_t sca_bytes = (size_t)N * D_FEAT * sizeof(float);
    const bool cached = ws_size >= sij_bytes + sca_bytes;

    float* s_ij      = (float*)d_ws;
    float* scattered = cached ? (float*)((char*)d_ws + sij_bytes)
                              : (float*)d_ws;   // path B only needs N*8 floats

    dim3 blk(256);
    dim3 gE((E + 255) / 256);
    dim3 gN((N + 255) / 256);

    // out = x_d @ Wf0.T ; scattered = 0
    node_init_kernel<<<gN, blk, 0, stream>>>(x_d, Wf[0], out, scattered, N);

    if (cached) {
        edge_mlp_kernel<<<gE, blk, 0, stream>>>(
            x_s, x_d, edge_attr, W1, b1, W2, b2, ei, E, s_ij);
        for (int k = 0; k < 2; ++k) {
            edge_step_cached_kernel<<<gE, blk, 0, stream>>>(
                out, s_ij, ei, E, scattered);
            node_update_kernel<<<gN, blk, 0, stream>>>(out, scattered, Wf[k + 1], N);
        }
    } else {
        for (int k = 0; k < 2; ++k) {
            edge_step_fused_kernel<<<gE, blk, 0, stream>>>(
                x_s, x_d, edge_attr, W1, b1, W2, b2, out, ei, E, scattered);
            node_update_kernel<<<gN, blk, 0, stream>>>(out, scattered, Wf[k + 1], N);
        }
    }
}

// Round 2
// 435.376 us; speedup vs baseline: 3.4316x; 3.4316x over previous
//
#include <hip/hip_runtime.h>
#include <hip/hip_fp16.h>

#define S_FEAT 16
#define D_FEAT 8
#define E_FEAT 4
#define EDGE_IN 52   // E_FEAT + 2*S_FEAT + 2*D_FEAT
#define HIDDEN 16    // 2*D_FEAT
#define SCAN_CHUNK 2048  // elements per scan block (256 thr * 8)

// ---------------------------------------------------------------------------
// Per-edge MLP (shared by both paths)
// ---------------------------------------------------------------------------
__device__ __forceinline__ void mlp_sij(
    const float* __restrict__ x_s, const float* __restrict__ x_d,
    const float* __restrict__ edge_attr,
    const float* __restrict__ W1, const float* __restrict__ b1,
    const float* __restrict__ W2, const float* __restrict__ b2,
    int row, int col, int e, float s[D_FEAT])
{
    float in[EDGE_IN];
    {
        const float4* p = (const float4*)(x_s + (size_t)row * S_FEAT);
#pragma unroll
        for (int q = 0; q < 4; ++q) {
            float4 v = p[q];
            in[q * 4 + 0] = v.x; in[q * 4 + 1] = v.y;
            in[q * 4 + 2] = v.z; in[q * 4 + 3] = v.w;
        }
    }
    {
        const float4* p = (const float4*)(x_s + (size_t)col * S_FEAT);
#pragma unroll
        for (int q = 0; q < 4; ++q) {
            float4 v = p[q];
            in[16 + q * 4 + 0] = v.x; in[16 + q * 4 + 1] = v.y;
            in[16 + q * 4 + 2] = v.z; in[16 + q * 4 + 3] = v.w;
        }
    }
    {
        const float4* p = (const float4*)(x_d + (size_t)row * D_FEAT);
#pragma unroll
        for (int q = 0; q < 2; ++q) {
            float4 v = p[q];
            in[32 + q * 4 + 0] = v.x; in[32 + q * 4 + 1] = v.y;
            in[32 + q * 4 + 2] = v.z; in[32 + q * 4 + 3] = v.w;
        }
    }
    {
        const float4* p = (const float4*)(x_d + (size_t)col * D_FEAT);
#pragma unroll
        for (int q = 0; q < 2; ++q) {
            float4 v = p[q];
            in[40 + q * 4 + 0] = v.x; in[40 + q * 4 + 1] = v.y;
            in[40 + q * 4 + 2] = v.z; in[40 + q * 4 + 3] = v.w;
        }
    }
    {
        float4 v = *(const float4*)(edge_attr + (size_t)e * E_FEAT);
        in[48] = v.x; in[49] = v.y; in[50] = v.z; in[51] = v.w;
    }

    float h[HIDDEN];
#pragma unroll
    for (int i = 0; i < HIDDEN; ++i) {
        float acc = b1[i];
#pragma unroll
        for (int j = 0; j < EDGE_IN; ++j)
            acc = fmaf(in[j], W1[i * EDGE_IN + j], acc);
        h[i] = acc > 0.f ? acc : 0.f;
    }

    float nrm2 = 0.f;
#pragma unroll
    for (int i = 0; i < D_FEAT; ++i) {
        float acc = b2[i];
#pragma unroll
        for (int j = 0; j < HIDDEN; ++j)
            acc = fmaf(h[j], W2[i * HIDDEN + j], acc);
        s[i] = acc;
        nrm2 = fmaf(acc, acc, nrm2);
    }
    float nrm = sqrtf(nrm2);
    float inv = nrm > 0.f ? 1.f / nrm : 0.f;
#pragma unroll
    for (int i = 0; i < D_FEAT; ++i) s[i] *= inv;
}

// ---------------------------------------------------------------------------
// Sort pipeline: counting sort of edges by col -> CSR
// ---------------------------------------------------------------------------
__global__ __launch_bounds__(256) void zero_counts_kernel(int* __restrict__ counts, int N)
{
    int i = blockIdx.x * blockDim.x + threadIdx.x;
    if (i < N) counts[i] = 0;
}

__global__ __launch_bounds__(256) void hist_kernel(
    const int* __restrict__ ei, int E, int N, int* __restrict__ counts)
{
    int e = blockIdx.x * blockDim.x + threadIdx.x;
    if (e >= E) return;
    int col = ei[E + e];
    atomicAdd(&counts[col], 1);
}

// per-block exclusive scan of counts -> offsets (partial), block totals
__global__ __launch_bounds__(256) void scan_local_kernel(
    const int* __restrict__ counts, int* __restrict__ partial,
    int* __restrict__ blocksums, int N)
{
    __shared__ int sh[256];
    int b = blockIdx.x, t = threadIdx.x;
    int base = b * SCAN_CHUNK + t * 8;
    int v[8];
    int run = 0;
#pragma unroll
    for (int j = 0; j < 8; ++j) {
        int c = (base + j < N) ? counts[base + j] : 0;
        v[j] = run;            // exclusive within thread
        run += c;
    }
    sh[t] = run;
    __syncthreads();
#pragma unroll
    for (int st = 1; st < 256; st <<= 1) {
        int x = (t >= st) ? sh[t - st] : 0;
        __syncthreads();
        sh[t] += x;
        __syncthreads();
    }
    int excl = sh[t] - run;    // exclusive across threads
    if (t == 255) blocksums[b] = sh[255];
#pragma unroll
    for (int j = 0; j < 8; ++j)
        if (base + j < N) partial[base + j] = excl + v[j];
}

__global__ void scan_blk_kernel(int* __restrict__ blocksums, int NB)
{
    if (threadIdx.x == 0) {
        int run = 0;
        for (int i = 0; i < NB; ++i) { int c = blocksums[i]; blocksums[i] = run; run += c; }
    }
}

__global__ __launch_bounds__(256) void scan_add_kernel(
    int* __restrict__ offsets, int* __restrict__ cursor,
    const int* __restrict__ blocksums, int N, int E)
{
    int i = blockIdx.x * blockDim.x + threadIdx.x;
    if (i < N) {
        int off = offsets[i] + blocksums[i / SCAN_CHUNK];
        offsets[i] = off;
        cursor[i]  = off;
    } else if (i == N) {
        offsets[N] = E;
    }
}

// ---------------------------------------------------------------------------
// MLP + scatter to sorted position (CSR order by col)
// ---------------------------------------------------------------------------
__global__ __launch_bounds__(256) void mlp_scatter_kernel(
    const float* __restrict__ x_s, const float* __restrict__ x_d,
    const float* __restrict__ edge_attr,
    const float* __restrict__ W1, const float* __restrict__ b1,
    const float* __restrict__ W2, const float* __restrict__ b2,
    const int* __restrict__ ei, int E,
    int* __restrict__ cursor, __half* __restrict__ s_srt, int* __restrict__ row_srt)
{
    int e = blockIdx.x * blockDim.x + threadIdx.x;
    if (e >= E) return;
    int row = ei[e], col = ei[E + e];
    float s[D_FEAT];
    mlp_sij(x_s, x_d, edge_attr, W1, b1, W2, b2, row, col, e, s);
    int pos = atomicAdd(&cursor[col], 1);
    __half h[8];
#pragma unroll
    for (int i = 0; i < 8; ++i) h[i] = __float2half(s[i]);
    *(float4*)(s_srt + (size_t)pos * 8) = *(const float4*)h;
    row_srt[pos] = row;
}

// ---------------------------------------------------------------------------
// out0 = x_d @ Wf0.T ; mask0 = rowsum != 0
// ---------------------------------------------------------------------------
__global__ __launch_bounds__(256) void node_init_kernel(
    const float* __restrict__ x_d, const float* __restrict__ Wf0,
    float* __restrict__ out, unsigned char* __restrict__ mask, int N)
{
    int n = blockIdx.x * blockDim.x + threadIdx.x;
    if (n >= N) return;
    float xd[D_FEAT];
    {
        const float4* p = (const float4*)(x_d + (size_t)n * D_FEAT);
        float4 a = p[0], b = p[1];
        xd[0] = a.x; xd[1] = a.y; xd[2] = a.z; xd[3] = a.w;
        xd[4] = b.x; xd[5] = b.y; xd[6] = b.z; xd[7] = b.w;
    }
    float o[D_FEAT];
    float rs = 0.f;
#pragma unroll
    for (int i = 0; i < D_FEAT; ++i) {
        float acc = 0.f;
#pragma unroll
        for (int j = 0; j < D_FEAT; ++j)
            acc = fmaf(xd[j], Wf0[i * D_FEAT + j], acc);
        o[i] = acc;
        rs += acc;
    }
    float4* op = (float4*)(out + (size_t)n * D_FEAT);
    op[0] = make_float4(o[0], o[1], o[2], o[3]);
    op[1] = make_float4(o[4], o[5], o[6], o[7]);
    mask[n] = (rs != 0.f) ? 1 : 0;
}

// ---------------------------------------------------------------------------
// One propagation step, CSR segment-sum, no atomics.
// 1 wave per node; lane = (e_sub<<3) | f.  Fuses the 8x8 filter matmul,
// the out update, and the next-step mask computation.
// ---------------------------------------------------------------------------
__global__ __launch_bounds__(256) void csr_step_kernel(
    const float* __restrict__ out_in, float* __restrict__ out_out,
    const unsigned char* __restrict__ mask_in, unsigned char* __restrict__ mask_out,
    const int* __restrict__ offsets, const int* __restrict__ row_srt,
    const __half* __restrict__ s_srt, const float* __restrict__ Wf, int N)
{
    int lane = threadIdx.x & 63;
    int node = blockIdx.x * 4 + (threadIdx.x >> 6);
    if (node >= N) return;
    int e_sub = lane >> 3, f = lane & 7;
    int beg = offsets[node], end = offsets[node + 1];
    float outc = out_in[(size_t)node * 8 + f];
    int mc = mask_in[node];
    float acc = 0.f;
    for (int base = beg; base < end; base += 8) {
        int e = base + e_sub;
        bool valid = e < end;
        int row = valid ? row_srt[e] : node;
        float s = valid ? __half2float(s_srt[(size_t)e * 8 + f]) : 0.f;
        float outr = out_in[(size_t)row * 8 + f];
        int m = mc | (int)mask_in[row];
        acc += (m != 0) ? (outc - outr) * s : 0.f;   // s==0 for invalid lanes
    }
    // reduce over the 8 e_sub groups (stride 8,16,32 keeps f fixed)
    acc += __shfl_xor(acc, 8);
    acc += __shfl_xor(acc, 16);
    acc += __shfl_xor(acc, 32);
    // out_new[f] = outc[f] + sum_j Wf[f][j] * acc[j]
    float upd = 0.f;
#pragma unroll
    for (int j = 0; j < 8; ++j) {
        float aj = __shfl(acc, (lane & ~7) | j);
        upd = fmaf(Wf[f * 8 + j], aj, upd);
    }
    float o = outc + upd;
    float rs = o;
    rs += __shfl_xor(rs, 1);
    rs += __shfl_xor(rs, 2);
    rs += __shfl_xor(rs, 4);
    if (e_sub == 0) {
        out_out[(size_t)node * 8 + f] = o;
        if (f == 0) mask_out[node] = (rs != 0.f) ? 1 : 0;
    }
}

// ---------------------------------------------------------------------------
// Fallback path (ws too small): round-1 fused atomic kernels
// ---------------------------------------------------------------------------
__global__ __launch_bounds__(256) void fb_node_init_kernel(
    const float* __restrict__ x_d, const float* __restrict__ Wf0,
    float* __restrict__ out, float* __restrict__ scattered, int N)
{
    int n = blockIdx.x * blockDim.x + threadIdx.x;
    if (n >= N) return;
    float xd[D_FEAT];
    const float4* p = (const float4*)(x_d + (size_t)n * D_FEAT);
    float4 a = p[0], b = p[1];
    xd[0] = a.x; xd[1] = a.y; xd[2] = a.z; xd[3] = a.w;
    xd[4] = b.x; xd[5] = b.y; xd[6] = b.z; xd[7] = b.w;
    float o[D_FEAT];
#pragma unroll
    for (int i = 0; i < D_FEAT; ++i) {
        float acc = 0.f;
#pragma unroll
        for (int j = 0; j < D_FEAT; ++j)
            acc = fmaf(xd[j], Wf0[i * D_FEAT + j], acc);
        o[i] = acc;
    }
    float4* op = (float4*)(out + (size_t)n * D_FEAT);
    op[0] = make_float4(o[0], o[1], o[2], o[3]);
    op[1] = make_float4(o[4], o[5], o[6], o[7]);
    float4* sp = (float4*)(scattered + (size_t)n * D_FEAT);
    sp[0] = make_float4(0.f, 0.f, 0.f, 0.f);
    sp[1] = make_float4(0.f, 0.f, 0.f, 0.f);
}

__global__ __launch_bounds__(256) void fb_edge_step_kernel(
    const float* __restrict__ x_s, const float* __restrict__ x_d,
    const float* __restrict__ edge_attr,
    const float* __restrict__ W1, const float* __restrict__ b1,
    const float* __restrict__ W2, const float* __restrict__ b2,
    const float* __restrict__ out,
    const int* __restrict__ ei, int E, float* __restrict__ scattered)
{
    int e = blockIdx.x * blockDim.x + threadIdx.x;
    if (e >= E) return;
    int row = ei[e], col = ei[E + e];
    const float4* pr = (const float4*)(out + (size_t)row * D_FEAT);
    const float4* pc = (const float4*)(out + (size_t)col * D_FEAT);
    float4 r0 = pr[0], r1 = pr[1], c0 = pc[0], c1 = pc[1];
    float srow = r0.x + r0.y + r0.z + r0.w + r1.x + r1.y + r1.z + r1.w;
    float scol = c0.x + c0.y + c0.z + c0.w + c1.x + c1.y + c1.z + c1.w;
    if (srow == 0.f && scol == 0.f) return;
    float s[D_FEAT];
    mlp_sij(x_s, x_d, edge_attr, W1, b1, W2, b2, row, col, e, s);
    float* dst = scattered + (size_t)col * D_FEAT;
    atomicAdd(dst + 0, (c0.x - r0.x) * s[0]);
    atomicAdd(dst + 1, (c0.y - r0.y) * s[1]);
    atomicAdd(dst + 2, (c0.z - r0.z) * s[2]);
    atomicAdd(dst + 3, (c0.w - r0.w) * s[3]);
    atomicAdd(dst + 4, (c1.x - r1.x) * s[4]);
    atomicAdd(dst + 5, (c1.y - r1.y) * s[5]);
    atomicAdd(dst + 6, (c1.z - r1.z) * s[6]);
    atomicAdd(dst + 7, (c1.w - r1.w) * s[7]);
}

__global__ __launch_bounds__(256) void fb_node_update_kernel(
    float* __restrict__ out, float* __restrict__ scattered,
    const float* __restrict__ Wf, int N)
{
    int n = blockIdx.x * blockDim.x + threadIdx.x;
    if (n >= N) return;
    float sc[D_FEAT];
    float4* sp = (float4*)(scattered + (size_t)n * D_FEAT);
    float4 a = sp[0], b = sp[1];
    sc[0] = a.x; sc[1] = a.y; sc[2] = a.z; sc[3] = a.w;
    sc[4] = b.x; sc[5] = b.y; sc[6] = b.z; sc[7] = b.w;
    sp[0] = make_float4(0.f, 0.f, 0.f, 0.f);
    sp[1] = make_float4(0.f, 0.f, 0.f, 0.f);
    float4* op = (float4*)(out + (size_t)n * D_FEAT);
    float4 o0 = op[0], o1 = op[1];
    float o[D_FEAT] = {o0.x, o0.y, o0.z, o0.w, o1.x, o1.y, o1.z, o1.w};
#pragma unroll
    for (int i = 0; i < D_FEAT; ++i) {
        float acc = 0.f;
#pragma unroll
        for (int j = 0; j < D_FEAT; ++j)
            acc = fmaf(sc[j], Wf[i * D_FEAT + j], acc);
        o[i] += acc;
    }
    op[0] = make_float4(o[0], o[1], o[2], o[3]);
    op[1] = make_float4(o[4], o[5], o[6], o[7]);
}

// ---------------------------------------------------------------------------
extern "C" void kernel_launch(void* const* d_in, const int* in_sizes, int n_in,
                              void* d_out, int out_size, void* d_ws, size_t ws_size,
                              hipStream_t stream) {
    const float* x_s       = (const float*)d_in[0];
    const float* x_d       = (const float*)d_in[1];
    const float* edge_attr = (const float*)d_in[2];
    const float* W1        = (const float*)d_in[3];
    const float* b1        = (const float*)d_in[4];
    const float* W2        = (const float*)d_in[5];
    const float* b2        = (const float*)d_in[6];
    const float* Wf[3]     = {(const float*)d_in[7], (const float*)d_in[8],
                              (const float*)d_in[9]};
    const int*   ei        = (const int*)d_in[10];

    const int N = in_sizes[1] / D_FEAT;
    const int E = in_sizes[10] / 2;

    float* out = (float*)d_out;

    // ---- workspace layout (CSR path) ----
    size_t off = 0;
    auto carve = [&](size_t bytes) { size_t p = off; off = (off + bytes + 255) & ~255ULL; return p; };
    size_t o_counts  = carve((size_t)(N + 1) * 4);
    size_t o_offsets = carve((size_t)(N + 1) * 4);
    size_t o_cursor  = carve((size_t)(N + 1) * 4);
    size_t o_bsums   = carve(256 * 4);
    size_t o_maskA   = carve((size_t)N);
    size_t o_maskB   = carve((size_t)N);
    size_t o_bufA    = carve((size_t)N * D_FEAT * 4);
    size_t o_rowsrt  = carve((size_t)E * 4);
    size_t o_ssrt    = carve((size_t)E * D_FEAT * 2);
    const size_t need = off;

    dim3 blk(256);
    dim3 gE((E + 255) / 256);
    dim3 gN((N + 255) / 256);

    if (ws_size >= need) {
        char* ws = (char*)d_ws;
        int*   counts  = (int*)(ws + o_counts);
        int*   offsets = (int*)(ws + o_offsets);
        int*   cursor  = (int*)(ws + o_cursor);
        int*   bsums   = (int*)(ws + o_bsums);
        unsigned char* maskA = (unsigned char*)(ws + o_maskA);
        unsigned char* maskB = (unsigned char*)(ws + o_maskB);
        float* bufA    = (float*)(ws + o_bufA);
        int*   row_srt = (int*)(ws + o_rowsrt);
        __half* s_srt  = (__half*)(ws + o_ssrt);

        const int NB = (N + SCAN_CHUNK - 1) / SCAN_CHUNK;

        zero_counts_kernel<<<gN, blk, 0, stream>>>(counts, N);
        hist_kernel<<<gE, blk, 0, stream>>>(ei, E, N, counts);
        scan_local_kernel<<<dim3(NB), blk, 0, stream>>>(counts, offsets, bsums, N);
        scan_blk_kernel<<<dim3(1), dim3(64), 0, stream>>>(bsums, NB);
        scan_add_kernel<<<dim3((N + 256) / 256), blk, 0, stream>>>(offsets, cursor, bsums, N, E);

        node_init_kernel<<<gN, blk, 0, stream>>>(x_d, Wf[0], out, maskA, N);
        mlp_scatter_kernel<<<gE, blk, 0, stream>>>(
            x_s, x_d, edge_attr, W1, b1, W2, b2, ei, E, cursor, s_srt, row_srt);

        dim3 gC((N + 3) / 4);  // 4 nodes (waves) per block
        csr_step_kernel<<<gC, blk, 0, stream>>>(
            out, bufA, maskA, maskB, offsets, row_srt, s_srt, Wf[1], N);
        csr_step_kernel<<<gC, blk, 0, stream>>>(
            bufA, out, maskB, maskA, offsets, row_srt, s_srt, Wf[2], N);
    } else {
        // fallback: fused atomic path, needs only N*8 floats
        float* scattered = (float*)d_ws;
        fb_node_init_kernel<<<gN, blk, 0, stream>>>(x_d, Wf[0], out, scattered, N);
        for (int k = 0; k < 2; ++k) {
            fb_edge_step_kernel<<<gE, blk, 0, stream>>>(
                x_s, x_d, edge_attr, W1, b1, W2, b2, out, ei, E, scattered);
            fb_node_update_kernel<<<gN, blk, 0, stream>>>(out, scattered, Wf[k + 1], N);
        }
    }
}

// Round 3
// 419.659 us; speedup vs baseline: 3.5601x; 1.0375x over previous
//
#include <hip/hip_runtime.h>

#define S_FEAT 16
#define D_FEAT 8
#define E_FEAT 4
#define EDGE_IN 52   // E_FEAT + 2*S_FEAT + 2*D_FEAT
#define HIDDEN 16    // 2*D_FEAT
#define SCAN_CHUNK 2048  // elements per scan block (256 thr * 8)
#define NSUB 8           // histogram copies

typedef unsigned int uint4v __attribute__((ext_vector_type(4)));

// ---------------------------------------------------------------------------
// Per-edge MLP (shared by both paths)
// ---------------------------------------------------------------------------
__device__ __forceinline__ void mlp_sij(
    const float* __restrict__ x_s, const float* __restrict__ x_d,
    const float* __restrict__ edge_attr,
    const float* __restrict__ W1, const float* __restrict__ b1,
    const float* __restrict__ W2, const float* __restrict__ b2,
    int row, int col, int e, float s[D_FEAT])
{
    float in[EDGE_IN];
    {
        const float4* p = (const float4*)(x_s + (size_t)row * S_FEAT);
#pragma unroll
        for (int q = 0; q < 4; ++q) {
            float4 v = p[q];
            in[q * 4 + 0] = v.x; in[q * 4 + 1] = v.y;
            in[q * 4 + 2] = v.z; in[q * 4 + 3] = v.w;
        }
    }
    {
        const float4* p = (const float4*)(x_s + (size_t)col * S_FEAT);
#pragma unroll
        for (int q = 0; q < 4; ++q) {
            float4 v = p[q];
            in[16 + q * 4 + 0] = v.x; in[16 + q * 4 + 1] = v.y;
            in[16 + q * 4 + 2] = v.z; in[16 + q * 4 + 3] = v.w;
        }
    }
    {
        const float4* p = (const float4*)(x_d + (size_t)row * D_FEAT);
#pragma unroll
        for (int q = 0; q < 2; ++q) {
            float4 v = p[q];
            in[32 + q * 4 + 0] = v.x; in[32 + q * 4 + 1] = v.y;
            in[32 + q * 4 + 2] = v.z; in[32 + q * 4 + 3] = v.w;
        }
    }
    {
        const float4* p = (const float4*)(x_d + (size_t)col * D_FEAT);
#pragma unroll
        for (int q = 0; q < 2; ++q) {
            float4 v = p[q];
            in[40 + q * 4 + 0] = v.x; in[40 + q * 4 + 1] = v.y;
            in[40 + q * 4 + 2] = v.z; in[40 + q * 4 + 3] = v.w;
        }
    }
    {
        float4 v = *(const float4*)(edge_attr + (size_t)e * E_FEAT);
        in[48] = v.x; in[49] = v.y; in[50] = v.z; in[51] = v.w;
    }

    float h[HIDDEN];
#pragma unroll
    for (int i = 0; i < HIDDEN; ++i) {
        float acc = b1[i];
#pragma unroll
        for (int j = 0; j < EDGE_IN; ++j)
            acc = fmaf(in[j], W1[i * EDGE_IN + j], acc);
        h[i] = acc > 0.f ? acc : 0.f;
    }

    float nrm2 = 0.f;
#pragma unroll
    for (int i = 0; i < D_FEAT; ++i) {
        float acc = b2[i];
#pragma unroll
        for (int j = 0; j < HIDDEN; ++j)
            acc = fmaf(h[j], W2[i * HIDDEN + j], acc);
        s[i] = acc;
        nrm2 = fmaf(acc, acc, nrm2);
    }
    float nrm = sqrtf(nrm2);
    float inv = nrm > 0.f ? 1.f / nrm : 0.f;
#pragma unroll
    for (int i = 0; i < D_FEAT; ++i) s[i] *= inv;
}

// ---------------------------------------------------------------------------
// 16B edge record: 8 x 12-bit fixed-point s (|s|<=1) in words x,y,z; row in w.
// ---------------------------------------------------------------------------
__device__ __forceinline__ uint4v pack_rec(const float s[8], int row)
{
    int q[8];
#pragma unroll
    for (int i = 0; i < 8; ++i) {
        float v = fminf(fmaxf(s[i] * 2047.f, -2047.f), 2047.f);
        q[i] = (int)rintf(v) & 0xFFF;
    }
    uint4v r;
    r[0] = (unsigned)(q[0] | (q[1] << 12) | (q[2] << 24));
    r[1] = (unsigned)((q[2] >> 8) | (q[3] << 4) | (q[4] << 16) | (q[5] << 28));
    r[2] = (unsigned)((q[5] >> 4) | (q[6] << 8) | (q[7] << 20));
    r[3] = (unsigned)row;
    return r;
}

__device__ __forceinline__ float rec_s(uint4v r, int f)
{
    int off = f * 12;
    unsigned lo = off < 32 ? r[0] : (off < 64 ? r[1] : r[2]);
    unsigned hi = off < 32 ? r[1] : (off < 64 ? r[2] : 0u);
    unsigned sh = (unsigned)off & 31u;
    unsigned long long both = ((unsigned long long)hi << 32) | lo;
    int q = ((int)((unsigned)(both >> sh) << 20)) >> 20;   // sext 12-bit
    return (float)q * (1.f / 2047.f);
}

// ---------------------------------------------------------------------------
// Sort pipeline: counting sort of edges by col -> CSR
// ---------------------------------------------------------------------------
__global__ __launch_bounds__(256) void zero_counts_kernel(int* __restrict__ counts, int M)
{
    int i = blockIdx.x * blockDim.x + threadIdx.x;
    if (i < M) counts[i] = 0;
}

__global__ __launch_bounds__(256) void hist_kernel(
    const int* __restrict__ ei, int E, int N, int* __restrict__ counts8)
{
    int e = blockIdx.x * blockDim.x + threadIdx.x;
    if (e >= E) return;
    int col = ei[E + e];
    atomicAdd(&counts8[(threadIdx.x & (NSUB - 1)) * N + col], 1);
}

// per-block exclusive scan of summed counts -> offsets (partial), block totals
__global__ __launch_bounds__(256) void scan_local_kernel(
    const int* __restrict__ counts8, int* __restrict__ partial,
    int* __restrict__ blocksums, int N)
{
    __shared__ int sh[256];
    int b = blockIdx.x, t = threadIdx.x;
    int base = b * SCAN_CHUNK + t * 8;
    int v[8];
    int run = 0;
#pragma unroll
    for (int j = 0; j < 8; ++j) {
        int c = 0;
        if (base + j < N) {
#pragma unroll
            for (int s8 = 0; s8 < NSUB; ++s8)
                c += counts8[s8 * N + base + j];
        }
        v[j] = run;            // exclusive within thread
        run += c;
    }
    sh[t] = run;
    __syncthreads();
#pragma unroll
    for (int st = 1; st < 256; st <<= 1) {
        int x = (t >= st) ? sh[t - st] : 0;
        __syncthreads();
        sh[t] += x;
        __syncthreads();
    }
    int excl = sh[t] - run;    // exclusive across threads
    if (t == 255) blocksums[b] = sh[255];
#pragma unroll
    for (int j = 0; j < 8; ++j)
        if (base + j < N) partial[base + j] = excl + v[j];
}

__global__ void scan_blk_kernel(int* __restrict__ blocksums, int NB)
{
    if (threadIdx.x == 0) {
        int run = 0;
        for (int i = 0; i < NB; ++i) { int c = blocksums[i]; blocksums[i] = run; run += c; }
    }
}

__global__ __launch_bounds__(256) void scan_add_kernel(
    int* __restrict__ offsets, int* __restrict__ cursor,
    const int* __restrict__ blocksums, int N, int E)
{
    int i = blockIdx.x * blockDim.x + threadIdx.x;
    if (i < N) {
        int off = offsets[i] + blocksums[i / SCAN_CHUNK];
        offsets[i] = off;
        cursor[i]  = off;
    } else if (i == N) {
        offsets[N] = E;
    }
}

// ---------------------------------------------------------------------------
// MLP + single 16B scattered record store (sorted position by col)
// ---------------------------------------------------------------------------
__global__ __launch_bounds__(256) void mlp_scatter_kernel(
    const float* __restrict__ x_s, const float* __restrict__ x_d,
    const float* __restrict__ edge_attr,
    const float* __restrict__ W1, const float* __restrict__ b1,
    const float* __restrict__ W2, const float* __restrict__ b2,
    const int* __restrict__ ei, int E,
    int* __restrict__ cursor, uint4v* __restrict__ recs)
{
    int e = blockIdx.x * blockDim.x + threadIdx.x;
    if (e >= E) return;
    int row = ei[e], col = ei[E + e];
    float s[D_FEAT];
    mlp_sij(x_s, x_d, edge_attr, W1, b1, W2, b2, row, col, e, s);
    uint4v rec = pack_rec(s, row);
    int pos = atomicAdd(&cursor[col], 1);
    __builtin_nontemporal_store(rec, recs + pos);
}

// ---------------------------------------------------------------------------
// out0 = x_d @ Wf0.T ; mask0 = rowsum != 0
// ---------------------------------------------------------------------------
__global__ __launch_bounds__(256) void node_init_kernel(
    const float* __restrict__ x_d, const float* __restrict__ Wf0,
    float* __restrict__ out, unsigned char* __restrict__ mask, int N)
{
    int n = blockIdx.x * blockDim.x + threadIdx.x;
    if (n >= N) return;
    float xd[D_FEAT];
    {
        const float4* p = (const float4*)(x_d + (size_t)n * D_FEAT);
        float4 a = p[0], b = p[1];
        xd[0] = a.x; xd[1] = a.y; xd[2] = a.z; xd[3] = a.w;
        xd[4] = b.x; xd[5] = b.y; xd[6] = b.z; xd[7] = b.w;
    }
    float o[D_FEAT];
    float rs = 0.f;
#pragma unroll
    for (int i = 0; i < D_FEAT; ++i) {
        float acc = 0.f;
#pragma unroll
        for (int j = 0; j < D_FEAT; ++j)
            acc = fmaf(xd[j], Wf0[i * D_FEAT + j], acc);
        o[i] = acc;
        rs += acc;
    }
    float4* op = (float4*)(out + (size_t)n * D_FEAT);
    op[0] = make_float4(o[0], o[1], o[2], o[3]);
    op[1] = make_float4(o[4], o[5], o[6], o[7]);
    mask[n] = (rs != 0.f) ? 1 : 0;
}

// ---------------------------------------------------------------------------
// One propagation step, CSR segment-sum, no atomics.
// 1 wave per node; lane = (e_sub<<3) | f.  Fuses the 8x8 filter matmul,
// the out update, and the next-step mask computation.
// ---------------------------------------------------------------------------
__global__ __launch_bounds__(256) void csr_step_kernel(
    const float* __restrict__ out_in, float* __restrict__ out_out,
    const unsigned char* __restrict__ mask_in, unsigned char* __restrict__ mask_out,
    const int* __restrict__ offsets, const uint4v* __restrict__ recs,
    const float* __restrict__ Wf, int N)
{
    int lane = threadIdx.x & 63;
    int node = blockIdx.x * 4 + (threadIdx.x >> 6);
    if (node >= N) return;
    int e_sub = lane >> 3, f = lane & 7;
    int beg = offsets[node], end = offsets[node + 1];
    float outc = out_in[(size_t)node * 8 + f];
    int mc = mask_in[node];
    float acc = 0.f;
    for (int base = beg; base < end; base += 8) {
        int e = base + e_sub;
        bool valid = e < end;
        uint4v rec = (uint4v)(0u);
        if (valid) rec = __builtin_nontemporal_load(recs + e);
        int row = (int)rec[3];                 // 0 for invalid lanes (s==0 anyway)
        float s = rec_s(rec, f);
        float outr = out_in[(size_t)row * 8 + f];
        int m = mc | (int)mask_in[row];
        acc += (m != 0) ? (outc - outr) * s : 0.f;
    }
    // reduce over the 8 e_sub groups (stride 8,16,32 keeps f fixed)
    acc += __shfl_xor(acc, 8);
    acc += __shfl_xor(acc, 16);
    acc += __shfl_xor(acc, 32);
    // out_new[f] = outc[f] + sum_j Wf[f][j] * acc[j]
    float upd = 0.f;
#pragma unroll
    for (int j = 0; j < 8; ++j) {
        float aj = __shfl(acc, (lane & ~7) | j);
        upd = fmaf(Wf[f * 8 + j], aj, upd);
    }
    float o = outc + upd;
    float rs = o;
    rs += __shfl_xor(rs, 1);
    rs += __shfl_xor(rs, 2);
    rs += __shfl_xor(rs, 4);
    if (e_sub == 0) {
        out_out[(size_t)node * 8 + f] = o;
        if (f == 0) mask_out[node] = (rs != 0.f) ? 1 : 0;
    }
}

// ---------------------------------------------------------------------------
// Fallback path (ws too small): fused atomic kernels
// ---------------------------------------------------------------------------
__global__ __launch_bounds__(256) void fb_node_init_kernel(
    const float* __restrict__ x_d, const float* __restrict__ Wf0,
    float* __restrict__ out, float* __restrict__ scattered, int N)
{
    int n = blockIdx.x * blockDim.x + threadIdx.x;
    if (n >= N) return;
    float xd[D_FEAT];
    const float4* p = (const float4*)(x_d + (size_t)n * D_FEAT);
    float4 a = p[0], b = p[1];
    xd[0] = a.x; xd[1] = a.y; xd[2] = a.z; xd[3] = a.w;
    xd[4] = b.x; xd[5] = b.y; xd[6] = b.z; xd[7] = b.w;
    float o[D_FEAT];
#pragma unroll
    for (int i = 0; i < D_FEAT; ++i) {
        float acc = 0.f;
#pragma unroll
        for (int j = 0; j < D_FEAT; ++j)
            acc = fmaf(xd[j], Wf0[i * D_FEAT + j], acc);
        o[i] = acc;
    }
    float4* op = (float4*)(out + (size_t)n * D_FEAT);
    op[0] = make_float4(o[0], o[1], o[2], o[3]);
    op[1] = make_float4(o[4], o[5], o[6], o[7]);
    float4* sp = (float4*)(scattered + (size_t)n * D_FEAT);
    sp[0] = make_float4(0.f, 0.f, 0.f, 0.f);
    sp[1] = make_float4(0.f, 0.f, 0.f, 0.f);
}

__global__ __launch_bounds__(256) void fb_edge_step_kernel(
    const float* __restrict__ x_s, const float* __restrict__ x_d,
    const float* __restrict__ edge_attr,
    const float* __restrict__ W1, const float* __restrict__ b1,
    const float* __restrict__ W2, const float* __restrict__ b2,
    const float* __restrict__ out,
    const int* __restrict__ ei, int E, float* __restrict__ scattered)
{
    int e = blockIdx.x * blockDim.x + threadIdx.x;
    if (e >= E) return;
    int row = ei[e], col = ei[E + e];
    const float4* pr = (const float4*)(out + (size_t)row * D_FEAT);
    const float4* pc = (const float4*)(out + (size_t)col * D_FEAT);
    float4 r0 = pr[0], r1 = pr[1], c0 = pc[0], c1 = pc[1];
    float srow = r0.x + r0.y + r0.z + r0.w + r1.x + r1.y + r1.z + r1.w;
    float scol = c0.x + c0.y + c0.z + c0.w + c1.x + c1.y + c1.z + c1.w;
    if (srow == 0.f && scol == 0.f) return;
    float s[D_FEAT];
    mlp_sij(x_s, x_d, edge_attr, W1, b1, W2, b2, row, col, e, s);
    float* dst = scattered + (size_t)col * D_FEAT;
    atomicAdd(dst + 0, (c0.x - r0.x) * s[0]);
    atomicAdd(dst + 1, (c0.y - r0.y) * s[1]);
    atomicAdd(dst + 2, (c0.z - r0.z) * s[2]);
    atomicAdd(dst + 3, (c0.w - r0.w) * s[3]);
    atomicAdd(dst + 4, (c1.x - r1.x) * s[4]);
    atomicAdd(dst + 5, (c1.y - r1.y) * s[5]);
    atomicAdd(dst + 6, (c1.z - r1.z) * s[6]);
    atomicAdd(dst + 7, (c1.w - r1.w) * s[7]);
}

__global__ __launch_bounds__(256) void fb_node_update_kernel(
    float* __restrict__ out, float* __restrict__ scattered,
    const float* __restrict__ Wf, int N)
{
    int n = blockIdx.x * blockDim.x + threadIdx.x;
    if (n >= N) return;
    float sc[D_FEAT];
    float4* sp = (float4*)(scattered + (size_t)n * D_FEAT);
    float4 a = sp[0], b = sp[1];
    sc[0] = a.x; sc[1] = a.y; sc[2] = a.z; sc[3] = a.w;
    sc[4] = b.x; sc[5] = b.y; sc[6] = b.z; sc[7] = b.w;
    sp[0] = make_float4(0.f, 0.f, 0.f, 0.f);
    sp[1] = make_float4(0.f, 0.f, 0.f, 0.f);
    float4* op = (float4*)(out + (size_t)n * D_FEAT);
    float4 o0 = op[0], o1 = op[1];
    float o[D_FEAT] = {o0.x, o0.y, o0.z, o0.w, o1.x, o1.y, o1.z, o1.w};
#pragma unroll
    for (int i = 0; i < D_FEAT; ++i) {
        float acc = 0.f;
#pragma unroll
        for (int j = 0; j < D_FEAT; ++j)
            acc = fmaf(sc[j], Wf[i * D_FEAT + j], acc);
        o[i] += acc;
    }
    op[0] = make_float4(o[0], o[1], o[2], o[3]);
    op[1] = make_float4(o[4], o[5], o[6], o[7]);
}

// ---------------------------------------------------------------------------
extern "C" void kernel_launch(void* const* d_in, const int* in_sizes, int n_in,
                              void* d_out, int out_size, void* d_ws, size_t ws_size,
                              hipStream_t stream) {
    const float* x_s       = (const float*)d_in[0];
    const float* x_d       = (const float*)d_in[1];
    const float* edge_attr = (const float*)d_in[2];
    const float* W1        = (const float*)d_in[3];
    const float* b1        = (const float*)d_in[4];
    const float* W2        = (const float*)d_in[5];
    const float* b2        = (const float*)d_in[6];
    const float* Wf[3]     = {(const float*)d_in[7], (const float*)d_in[8],
                              (const float*)d_in[9]};
    const int*   ei        = (const int*)d_in[10];

    const int N = in_sizes[1] / D_FEAT;
    const int E = in_sizes[10] / 2;

    float* out = (float*)d_out;

    // ---- workspace layout (CSR path) ----
    size_t off = 0;
    auto carve = [&](size_t bytes) { size_t p = off; off = (off + bytes + 255) & ~255ULL; return p; };
    size_t o_counts  = carve((size_t)NSUB * N * 4);
    size_t o_offsets = carve((size_t)(N + 1) * 4);
    size_t o_cursor  = carve((size_t)(N + 1) * 4);
    size_t o_bsums   = carve(256 * 4);
    size_t o_maskA   = carve((size_t)N);
    size_t o_maskB   = carve((size_t)N);
    size_t o_bufA    = carve((size_t)N * D_FEAT * 4);
    size_t o_recs    = carve((size_t)E * 16);
    const size_t need = off;

    dim3 blk(256);
    dim3 gE((E + 255) / 256);
    dim3 gN((N + 255) / 256);

    if (ws_size >= need) {
        char* ws = (char*)d_ws;
        int*   counts8 = (int*)(ws + o_counts);
        int*   offsets = (int*)(ws + o_offsets);
        int*   cursor  = (int*)(ws + o_cursor);
        int*   bsums   = (int*)(ws + o_bsums);
        unsigned char* maskA = (unsigned char*)(ws + o_maskA);
        unsigned char* maskB = (unsigned char*)(ws + o_maskB);
        float* bufA    = (float*)(ws + o_bufA);
        uint4v* recs   = (uint4v*)(ws + o_recs);

        const int NB = (N + SCAN_CHUNK - 1) / SCAN_CHUNK;

        zero_counts_kernel<<<dim3((NSUB * N + 255) / 256), blk, 0, stream>>>(counts8, NSUB * N);
        hist_kernel<<<gE, blk, 0, stream>>>(ei, E, N, counts8);
        scan_local_kernel<<<dim3(NB), blk, 0, stream>>>(counts8, offsets, bsums, N);
        scan_blk_kernel<<<dim3(1), dim3(64), 0, stream>>>(bsums, NB);
        scan_add_kernel<<<dim3((N + 256) / 256), blk, 0, stream>>>(offsets, cursor, bsums, N, E);

        node_init_kernel<<<gN, blk, 0, stream>>>(x_d, Wf[0], out, maskA, N);
        mlp_scatter_kernel<<<gE, blk, 0, stream>>>(
            x_s, x_d, edge_attr, W1, b1, W2, b2, ei, E, cursor, recs);

        dim3 gC((N + 3) / 4);  // 4 nodes (waves) per block
        csr_step_kernel<<<gC, blk, 0, stream>>>(
            out, bufA, maskA, maskB, offsets, recs, Wf[1], N);
        csr_step_kernel<<<gC, blk, 0, stream>>>(
            bufA, out, maskB, maskA, offsets, recs, Wf[2], N);
    } else {
        // fallback: fused atomic path, needs only N*8 floats
        float* scattered = (float*)d_ws;
        fb_node_init_kernel<<<gN, blk, 0, stream>>>(x_d, Wf[0], out, scattered, N);
        for (int k = 0; k < 2; ++k) {
            fb_edge_step_kernel<<<gE, blk, 0, stream>>>(
                x_s, x_d, edge_attr, W1, b1, W2, b2, out, ei, E, scattered);
            fb_node_update_kernel<<<gN, blk, 0, stream>>>(out, scattered, Wf[k + 1], N);
        }
    }
}

// Round 4
// 386.474 us; speedup vs baseline: 3.8658x; 1.0859x over previous
//
#include <hip/hip_runtime.h>

#define S_FEAT 16
#define D_FEAT 8
#define E_FEAT 4
#define EDGE_IN 52   // E_FEAT + 2*S_FEAT + 2*D_FEAT
#define HIDDEN 16    // 2*D_FEAT
#define SCAN_CHUNK 2048  // elements per scan block (256 thr * 8)
#define NSUB 8           // histogram copies

typedef unsigned int uint4v __attribute__((ext_vector_type(4)));

// ---------------------------------------------------------------------------
// Full per-edge MLP (tier-B / fallback paths)
// ---------------------------------------------------------------------------
__device__ __forceinline__ void mlp_sij(
    const float* __restrict__ x_s, const float* __restrict__ x_d,
    const float* __restrict__ edge_attr,
    const float* __restrict__ W1, const float* __restrict__ b1,
    const float* __restrict__ W2, const float* __restrict__ b2,
    int row, int col, int e, float s[D_FEAT])
{
    float in[EDGE_IN];
    {
        const float4* p = (const float4*)(x_s + (size_t)row * S_FEAT);
#pragma unroll
        for (int q = 0; q < 4; ++q) {
            float4 v = p[q];
            in[q * 4 + 0] = v.x; in[q * 4 + 1] = v.y;
            in[q * 4 + 2] = v.z; in[q * 4 + 3] = v.w;
        }
    }
    {
        const float4* p = (const float4*)(x_s + (size_t)col * S_FEAT);
#pragma unroll
        for (int q = 0; q < 4; ++q) {
            float4 v = p[q];
            in[16 + q * 4 + 0] = v.x; in[16 + q * 4 + 1] = v.y;
            in[16 + q * 4 + 2] = v.z; in[16 + q * 4 + 3] = v.w;
        }
    }
    {
        const float4* p = (const float4*)(x_d + (size_t)row * D_FEAT);
#pragma unroll
        for (int q = 0; q < 2; ++q) {
            float4 v = p[q];
            in[32 + q * 4 + 0] = v.x; in[32 + q * 4 + 1] = v.y;
            in[32 + q * 4 + 2] = v.z; in[32 + q * 4 + 3] = v.w;
        }
    }
    {
        const float4* p = (const float4*)(x_d + (size_t)col * D_FEAT);
#pragma unroll
        for (int q = 0; q < 2; ++q) {
            float4 v = p[q];
            in[40 + q * 4 + 0] = v.x; in[40 + q * 4 + 1] = v.y;
            in[40 + q * 4 + 2] = v.z; in[40 + q * 4 + 3] = v.w;
        }
    }
    {
        float4 v = *(const float4*)(edge_attr + (size_t)e * E_FEAT);
        in[48] = v.x; in[49] = v.y; in[50] = v.z; in[51] = v.w;
    }

    float h[HIDDEN];
#pragma unroll
    for (int i = 0; i < HIDDEN; ++i) {
        float acc = b1[i];
#pragma unroll
        for (int j = 0; j < EDGE_IN; ++j)
            acc = fmaf(in[j], W1[i * EDGE_IN + j], acc);
        h[i] = acc > 0.f ? acc : 0.f;
    }

    float nrm2 = 0.f;
#pragma unroll
    for (int i = 0; i < D_FEAT; ++i) {
        float acc = b2[i];
#pragma unroll
        for (int j = 0; j < HIDDEN; ++j)
            acc = fmaf(h[j], W2[i * HIDDEN + j], acc);
        s[i] = acc;
        nrm2 = fmaf(acc, acc, nrm2);
    }
    float nrm = sqrtf(nrm2);
    float inv = nrm > 0.f ? 1.f / nrm : 0.f;
#pragma unroll
    for (int i = 0; i < D_FEAT; ++i) s[i] *= inv;
}

// ---------------------------------------------------------------------------
// 16B edge record: 8 x 12-bit fixed-point s (|s|<=1) in words x,y,z; row in w.
// ---------------------------------------------------------------------------
__device__ __forceinline__ uint4v pack_rec(const float s[8], int row)
{
    int q[8];
#pragma unroll
    for (int i = 0; i < 8; ++i) {
        float v = fminf(fmaxf(s[i] * 2047.f, -2047.f), 2047.f);
        q[i] = (int)rintf(v) & 0xFFF;
    }
    uint4v r;
    r[0] = (unsigned)(q[0] | (q[1] << 12) | (q[2] << 24));
    r[1] = (unsigned)((q[2] >> 8) | (q[3] << 4) | (q[4] << 16) | (q[5] << 28));
    r[2] = (unsigned)((q[5] >> 4) | (q[6] << 8) | (q[7] << 20));
    r[3] = (unsigned)row;
    return r;
}

__device__ __forceinline__ float rec_s(uint4v r, int f)
{
    int off = f * 12;
    unsigned lo = off < 32 ? r[0] : (off < 64 ? r[1] : r[2]);
    unsigned hi = off < 32 ? r[1] : (off < 64 ? r[2] : 0u);
    unsigned sh = (unsigned)off & 31u;
    unsigned long long both = ((unsigned long long)hi << 32) | lo;
    int q = ((int)((unsigned)(both >> sh) << 20)) >> 20;   // sext 12-bit
    return (float)q * (1.f / 2047.f);
}

// ---------------------------------------------------------------------------
// Sort pipeline: counting sort of edges by col -> CSR
// ---------------------------------------------------------------------------
__global__ __launch_bounds__(256) void zero_counts_kernel(int* __restrict__ counts, int M)
{
    int i = blockIdx.x * blockDim.x + threadIdx.x;
    if (i < M) counts[i] = 0;
}

__global__ __launch_bounds__(256) void hist_kernel(
    const int* __restrict__ ei, int E, int N, int* __restrict__ counts8)
{
    int e = blockIdx.x * blockDim.x + threadIdx.x;
    if (e >= E) return;
    int col = ei[E + e];
    atomicAdd(&counts8[(threadIdx.x & (NSUB - 1)) * N + col], 1);
}

// per-block exclusive scan of summed counts -> offsets (partial), block totals
__global__ __launch_bounds__(256) void scan_local_kernel(
    const int* __restrict__ counts8, int* __restrict__ partial,
    int* __restrict__ blocksums, int N)
{
    __shared__ int sh[256];
    int b = blockIdx.x, t = threadIdx.x;
    int base = b * SCAN_CHUNK + t * 8;
    int v[8];
    int run = 0;
#pragma unroll
    for (int j = 0; j < 8; ++j) {
        int c = 0;
        if (base + j < N) {
#pragma unroll
            for (int s8 = 0; s8 < NSUB; ++s8)
                c += counts8[s8 * N + base + j];
        }
        v[j] = run;            // exclusive within thread
        run += c;
    }
    sh[t] = run;
    __syncthreads();
#pragma unroll
    for (int st = 1; st < 256; st <<= 1) {
        int x = (t >= st) ? sh[t - st] : 0;
        __syncthreads();
        sh[t] += x;
        __syncthreads();
    }
    int excl = sh[t] - run;    // exclusive across threads
    if (t == 255) blocksums[b] = sh[255];
#pragma unroll
    for (int j = 0; j < 8; ++j)
        if (base + j < N) partial[base + j] = excl + v[j];
}

__global__ void scan_blk_kernel(int* __restrict__ blocksums, int NB)
{
    if (threadIdx.x == 0) {
        int run = 0;
        for (int i = 0; i < NB; ++i) { int c = blocksums[i]; blocksums[i] = run; run += c; }
    }
}

__global__ __launch_bounds__(256) void scan_add_kernel(
    int* __restrict__ offsets, int* __restrict__ cursor,
    const int* __restrict__ blocksums, int N, int E)
{
    int i = blockIdx.x * blockDim.x + threadIdx.x;
    if (i < N) {
        int off = offsets[i] + blocksums[i / SCAN_CHUNK];
        offsets[i] = off;
        cursor[i]  = off;
    } else if (i == N) {
        offsets[N] = E;
    }
}

// ---------------------------------------------------------------------------
// Tier A: per-node first-layer projections.
// PR[n] = W1[:,0:16] @ x_s[n] + W1[:,32:40] @ x_d[n] + b1   (bias folded)
// PC[n] = W1[:,16:32] @ x_s[n] + W1[:,40:48] @ x_d[n]
// ---------------------------------------------------------------------------
__global__ __launch_bounds__(256) void proj_kernel(
    const float* __restrict__ x_s, const float* __restrict__ x_d,
    const float* __restrict__ W1, const float* __restrict__ b1,
    float* __restrict__ PR, float* __restrict__ PC, int N)
{
    int n = blockIdx.x * blockDim.x + threadIdx.x;
    if (n >= N) return;
    float xs[S_FEAT], xd[D_FEAT];
    {
        const float4* p = (const float4*)(x_s + (size_t)n * S_FEAT);
#pragma unroll
        for (int q = 0; q < 4; ++q) {
            float4 v = p[q];
            xs[q * 4 + 0] = v.x; xs[q * 4 + 1] = v.y;
            xs[q * 4 + 2] = v.z; xs[q * 4 + 3] = v.w;
        }
        const float4* pd = (const float4*)(x_d + (size_t)n * D_FEAT);
        float4 a = pd[0], b = pd[1];
        xd[0] = a.x; xd[1] = a.y; xd[2] = a.z; xd[3] = a.w;
        xd[4] = b.x; xd[5] = b.y; xd[6] = b.z; xd[7] = b.w;
    }
    float pr[HIDDEN], pc[HIDDEN];
#pragma unroll
    for (int i = 0; i < HIDDEN; ++i) {
        const float* w = W1 + i * EDGE_IN;
        float a = b1[i], c = 0.f;
#pragma unroll
        for (int j = 0; j < S_FEAT; ++j) {
            a = fmaf(xs[j], w[j], a);
            c = fmaf(xs[j], w[16 + j], c);
        }
#pragma unroll
        for (int j = 0; j < D_FEAT; ++j) {
            a = fmaf(xd[j], w[32 + j], a);
            c = fmaf(xd[j], w[40 + j], c);
        }
        pr[i] = a; pc[i] = c;
    }
    float4* prp = (float4*)(PR + (size_t)n * HIDDEN);
    float4* pcp = (float4*)(PC + (size_t)n * HIDDEN);
#pragma unroll
    for (int q = 0; q < 4; ++q) {
        prp[q] = make_float4(pr[q * 4], pr[q * 4 + 1], pr[q * 4 + 2], pr[q * 4 + 3]);
        pcp[q] = make_float4(pc[q * 4], pc[q * 4 + 1], pc[q * 4 + 2], pc[q * 4 + 3]);
    }
}

// ---------------------------------------------------------------------------
// Tier A edge kernel: gather PR[row], PC[col]; add edge-attr projection;
// second layer; normalize; pack; scatter to sorted position.
// ---------------------------------------------------------------------------
__global__ __launch_bounds__(256) void mlp_scatter_proj_kernel(
    const float* __restrict__ PR, const float* __restrict__ PC,
    const float* __restrict__ edge_attr,
    const float* __restrict__ W1,
    const float* __restrict__ W2, const float* __restrict__ b2,
    const int* __restrict__ ei, int E,
    int* __restrict__ cursor, uint4v* __restrict__ recs)
{
    int e = blockIdx.x * blockDim.x + threadIdx.x;
    if (e >= E) return;
    int row = ei[e], col = ei[E + e];

    float pr[HIDDEN], pc[HIDDEN];
    {
        const float4* p = (const float4*)(PR + (size_t)row * HIDDEN);
        const float4* c = (const float4*)(PC + (size_t)col * HIDDEN);
#pragma unroll
        for (int q = 0; q < 4; ++q) {
            float4 a = p[q], b = c[q];
            pr[q * 4 + 0] = a.x; pr[q * 4 + 1] = a.y;
            pr[q * 4 + 2] = a.z; pr[q * 4 + 3] = a.w;
            pc[q * 4 + 0] = b.x; pc[q * 4 + 1] = b.y;
            pc[q * 4 + 2] = b.z; pc[q * 4 + 3] = b.w;
        }
    }
    float4 ea = *(const float4*)(edge_attr + (size_t)e * E_FEAT);

    float h[HIDDEN];
#pragma unroll
    for (int i = 0; i < HIDDEN; ++i) {
        const float* w = W1 + i * EDGE_IN + 48;
        float acc = pr[i] + pc[i];
        acc = fmaf(ea.x, w[0], acc);
        acc = fmaf(ea.y, w[1], acc);
        acc = fmaf(ea.z, w[2], acc);
        acc = fmaf(ea.w, w[3], acc);
        h[i] = acc > 0.f ? acc : 0.f;
    }

    float s[D_FEAT];
    float nrm2 = 0.f;
#pragma unroll
    for (int i = 0; i < D_FEAT; ++i) {
        float acc = b2[i];
#pragma unroll
        for (int j = 0; j < HIDDEN; ++j)
            acc = fmaf(h[j], W2[i * HIDDEN + j], acc);
        s[i] = acc;
        nrm2 = fmaf(acc, acc, nrm2);
    }
    float nrm = sqrtf(nrm2);
    float inv = nrm > 0.f ? 1.f / nrm : 0.f;
#pragma unroll
    for (int i = 0; i < D_FEAT; ++i) s[i] *= inv;

    uint4v rec = pack_rec(s, row);
    int pos = atomicAdd(&cursor[col], 1);
    __builtin_nontemporal_store(rec, recs + pos);
}

// ---------------------------------------------------------------------------
// Tier B edge kernel (no projection tables): full MLP per edge
// ---------------------------------------------------------------------------
__global__ __launch_bounds__(256) void mlp_scatter_direct_kernel(
    const float* __restrict__ x_s, const float* __restrict__ x_d,
    const float* __restrict__ edge_attr,
    const float* __restrict__ W1, const float* __restrict__ b1,
    const float* __restrict__ W2, const float* __restrict__ b2,
    const int* __restrict__ ei, int E,
    int* __restrict__ cursor, uint4v* __restrict__ recs)
{
    int e = blockIdx.x * blockDim.x + threadIdx.x;
    if (e >= E) return;
    int row = ei[e], col = ei[E + e];
    float s[D_FEAT];
    mlp_sij(x_s, x_d, edge_attr, W1, b1, W2, b2, row, col, e, s);
    uint4v rec = pack_rec(s, row);
    int pos = atomicAdd(&cursor[col], 1);
    __builtin_nontemporal_store(rec, recs + pos);
}

// ---------------------------------------------------------------------------
// out0 = x_d @ Wf0.T  (masks are derived on the fly in csr_step now)
// ---------------------------------------------------------------------------
__global__ __launch_bounds__(256) void node_init_kernel(
    const float* __restrict__ x_d, const float* __restrict__ Wf0,
    float* __restrict__ out, int N)
{
    int n = blockIdx.x * blockDim.x + threadIdx.x;
    if (n >= N) return;
    float xd[D_FEAT];
    {
        const float4* p = (const float4*)(x_d + (size_t)n * D_FEAT);
        float4 a = p[0], b = p[1];
        xd[0] = a.x; xd[1] = a.y; xd[2] = a.z; xd[3] = a.w;
        xd[4] = b.x; xd[5] = b.y; xd[6] = b.z; xd[7] = b.w;
    }
    float o[D_FEAT];
#pragma unroll
    for (int i = 0; i < D_FEAT; ++i) {
        float acc = 0.f;
#pragma unroll
        for (int j = 0; j < D_FEAT; ++j)
            acc = fmaf(xd[j], Wf0[i * D_FEAT + j], acc);
        o[i] = acc;
    }
    float4* op = (float4*)(out + (size_t)n * D_FEAT);
    op[0] = make_float4(o[0], o[1], o[2], o[3]);
    op[1] = make_float4(o[4], o[5], o[6], o[7]);
}

// ---------------------------------------------------------------------------
// One propagation step, CSR segment-sum, no atomics, masks computed from out.
// 1 wave per node; lane = (e_sub<<3) | f.
// ---------------------------------------------------------------------------
__global__ __launch_bounds__(256) void csr_step_kernel(
    const float* __restrict__ out_in, float* __restrict__ out_out,
    const int* __restrict__ offsets, const uint4v* __restrict__ recs,
    const float* __restrict__ Wf, int N)
{
    int lane = threadIdx.x & 63;
    int node = blockIdx.x * 4 + (threadIdx.x >> 6);
    if (node >= N) return;
    int e_sub = lane >> 3, f = lane & 7;
    int beg = offsets[node], end = offsets[node + 1];
    float outc = out_in[(size_t)node * 8 + f];
    // node row-sum over f within each e_sub octet -> mask(node)
    float sc = outc;
    sc += __shfl_xor(sc, 1); sc += __shfl_xor(sc, 2); sc += __shfl_xor(sc, 4);
    bool mc = (sc != 0.f);
    float acc = 0.f;
    for (int base = beg; base < end; base += 8) {
        int e = base + e_sub;
        bool valid = e < end;
        uint4v rec = (uint4v)(0u);
        if (valid) rec = __builtin_nontemporal_load(recs + e);
        int row = (int)rec[3];                 // 0 for invalid lanes (s==0 anyway)
        float s = rec_s(rec, f);
        float outr = out_in[(size_t)row * 8 + f];
        float sr = outr;                        // mask(row) from gathered values
        sr += __shfl_xor(sr, 1); sr += __shfl_xor(sr, 2); sr += __shfl_xor(sr, 4);
        bool m = mc || (sr != 0.f);
        acc += m ? (outc - outr) * s : 0.f;
    }
    // reduce over the 8 e_sub groups (stride 8,16,32 keeps f fixed)
    acc += __shfl_xor(acc, 8);
    acc += __shfl_xor(acc, 16);
    acc += __shfl_xor(acc, 32);
    // out_new[f] = outc[f] + sum_j Wf[f][j] * acc[j]
    float upd = 0.f;
#pragma unroll
    for (int j = 0; j < 8; ++j) {
        float aj = __shfl(acc, (lane & ~7) | j);
        upd = fmaf(Wf[f * 8 + j], aj, upd);
    }
    if (e_sub == 0)
        out_out[(size_t)node * 8 + f] = outc + upd;
}

// ---------------------------------------------------------------------------
// Tier C fallback (ws tiny): fused atomic kernels
// ---------------------------------------------------------------------------
__global__ __launch_bounds__(256) void fb_node_init_kernel(
    const float* __restrict__ x_d, const float* __restrict__ Wf0,
    float* __restrict__ out, float* __restrict__ scattered, int N)
{
    int n = blockIdx.x * blockDim.x + threadIdx.x;
    if (n >= N) return;
    float xd[D_FEAT];
    const float4* p = (const float4*)(x_d + (size_t)n * D_FEAT);
    float4 a = p[0], b = p[1];
    xd[0] = a.x; xd[1] = a.y; xd[2] = a.z; xd[3] = a.w;
    xd[4] = b.x; xd[5] = b.y; xd[6] = b.z; xd[7] = b.w;
    float o[D_FEAT];
#pragma unroll
    for (int i = 0; i < D_FEAT; ++i) {
        float acc = 0.f;
#pragma unroll
        for (int j = 0; j < D_FEAT; ++j)
            acc = fmaf(xd[j], Wf0[i * D_FEAT + j], acc);
        o[i] = acc;
    }
    float4* op = (float4*)(out + (size_t)n * D_FEAT);
    op[0] = make_float4(o[0], o[1], o[2], o[3]);
    op[1] = make_float4(o[4], o[5], o[6], o[7]);
    float4* sp = (float4*)(scattered + (size_t)n * D_FEAT);
    sp[0] = make_float4(0.f, 0.f, 0.f, 0.f);
    sp[1] = make_float4(0.f, 0.f, 0.f, 0.f);
}

__global__ __launch_bounds__(256) void fb_edge_step_kernel(
    const float* __restrict__ x_s, const float* __restrict__ x_d,
    const float* __restrict__ edge_attr,
    const float* __restrict__ W1, const float* __restrict__ b1,
    const float* __restrict__ W2, const float* __restrict__ b2,
    const float* __restrict__ out,
    const int* __restrict__ ei, int E, float* __restrict__ scattered)
{
    int e = blockIdx.x * blockDim.x + threadIdx.x;
    if (e >= E) return;
    int row = ei[e], col = ei[E + e];
    const float4* pr = (const float4*)(out + (size_t)row * D_FEAT);
    const float4* pc = (const float4*)(out + (size_t)col * D_FEAT);
    float4 r0 = pr[0], r1 = pr[1], c0 = pc[0], c1 = pc[1];
    float srow = r0.x + r0.y + r0.z + r0.w + r1.x + r1.y + r1.z + r1.w;
    float scol = c0.x + c0.y + c0.z + c0.w + c1.x + c1.y + c1.z + c1.w;
    if (srow == 0.f && scol == 0.f) return;
    float s[D_FEAT];
    mlp_sij(x_s, x_d, edge_attr, W1, b1, W2, b2, row, col, e, s);
    float* dst = scattered + (size_t)col * D_FEAT;
    atomicAdd(dst + 0, (c0.x - r0.x) * s[0]);
    atomicAdd(dst + 1, (c0.y - r0.y) * s[1]);
    atomicAdd(dst + 2, (c0.z - r0.z) * s[2]);
    atomicAdd(dst + 3, (c0.w - r0.w) * s[3]);
    atomicAdd(dst + 4, (c1.x - r1.x) * s[4]);
    atomicAdd(dst + 5, (c1.y - r1.y) * s[5]);
    atomicAdd(dst + 6, (c1.z - r1.z) * s[6]);
    atomicAdd(dst + 7, (c1.w - r1.w) * s[7]);
}

__global__ __launch_bounds__(256) void fb_node_update_kernel(
    float* __restrict__ out, float* __restrict__ scattered,
    const float* __restrict__ Wf, int N)
{
    int n = blockIdx.x * blockDim.x + threadIdx.x;
    if (n >= N) return;
    float sc[D_FEAT];
    float4* sp = (float4*)(scattered + (size_t)n * D_FEAT);
    float4 a = sp[0], b = sp[1];
    sc[0] = a.x; sc[1] = a.y; sc[2] = a.z; sc[3] = a.w;
    sc[4] = b.x; sc[5] = b.y; sc[6] = b.z; sc[7] = b.w;
    sp[0] = make_float4(0.f, 0.f, 0.f, 0.f);
    sp[1] = make_float4(0.f, 0.f, 0.f, 0.f);
    float4* op = (float4*)(out + (size_t)n * D_FEAT);
    float4 o0 = op[0], o1 = op[1];
    float o[D_FEAT] = {o0.x, o0.y, o0.z, o0.w, o1.x, o1.y, o1.z, o1.w};
#pragma unroll
    for (int i = 0; i < D_FEAT; ++i) {
        float acc = 0.f;
#pragma unroll
        for (int j = 0; j < D_FEAT; ++j)
            acc = fmaf(sc[j], Wf[i * D_FEAT + j], acc);
        o[i] += acc;
    }
    op[0] = make_float4(o[0], o[1], o[2], o[3]);
    op[1] = make_float4(o[4], o[5], o[6], o[7]);
}

// ---------------------------------------------------------------------------
extern "C" void kernel_launch(void* const* d_in, const int* in_sizes, int n_in,
                              void* d_out, int out_size, void* d_ws, size_t ws_size,
                              hipStream_t stream) {
    const float* x_s       = (const float*)d_in[0];
    const float* x_d       = (const float*)d_in[1];
    const float* edge_attr = (const float*)d_in[2];
    const float* W1        = (const float*)d_in[3];
    const float* b1        = (const float*)d_in[4];
    const float* W2        = (const float*)d_in[5];
    const float* b2        = (const float*)d_in[6];
    const float* Wf[3]     = {(const float*)d_in[7], (const float*)d_in[8],
                              (const float*)d_in[9]};
    const int*   ei        = (const int*)d_in[10];

    const int N = in_sizes[1] / D_FEAT;
    const int E = in_sizes[10] / 2;

    float* out = (float*)d_out;

    // ---- workspace layout ----
    size_t off = 0;
    auto carve = [&](size_t bytes) { size_t p = off; off = (off + bytes + 255) & ~255ULL; return p; };
    size_t o_counts  = carve((size_t)NSUB * N * 4);
    size_t o_offsets = carve((size_t)(N + 1) * 4);
    size_t o_cursor  = carve((size_t)(N + 1) * 4);
    size_t o_bsums   = carve(256 * 4);
    size_t o_bufA    = carve((size_t)N * D_FEAT * 4);
    size_t o_recs    = carve((size_t)E * 16);
    const size_t need_base = off;                       // tier B
    size_t o_PR      = carve((size_t)N * HIDDEN * 4);
    size_t o_PC      = carve((size_t)N * HIDDEN * 4);
    const size_t need_full = off;                       // tier A

    dim3 blk(256);
    dim3 gE((E + 255) / 256);
    dim3 gN((N + 255) / 256);

    if (ws_size >= need_base) {
        char* ws = (char*)d_ws;
        int*   counts8 = (int*)(ws + o_counts);
        int*   offsets = (int*)(ws + o_offsets);
        int*   cursor  = (int*)(ws + o_cursor);
        int*   bsums   = (int*)(ws + o_bsums);
        float* bufA    = (float*)(ws + o_bufA);
        uint4v* recs   = (uint4v*)(ws + o_recs);

        const int NB = (N + SCAN_CHUNK - 1) / SCAN_CHUNK;

        zero_counts_kernel<<<dim3((NSUB * N + 255) / 256), blk, 0, stream>>>(counts8, NSUB * N);
        hist_kernel<<<gE, blk, 0, stream>>>(ei, E, N, counts8);
        scan_local_kernel<<<dim3(NB), blk, 0, stream>>>(counts8, offsets, bsums, N);
        scan_blk_kernel<<<dim3(1), dim3(64), 0, stream>>>(bsums, NB);
        scan_add_kernel<<<dim3((N + 256) / 256), blk, 0, stream>>>(offsets, cursor, bsums, N, E);

        node_init_kernel<<<gN, blk, 0, stream>>>(x_d, Wf[0], out, N);

        if (ws_size >= need_full) {
            float* PR = (float*)(ws + o_PR);
            float* PC = (float*)(ws + o_PC);
            proj_kernel<<<gN, blk, 0, stream>>>(x_s, x_d, W1, b1, PR, PC, N);
            mlp_scatter_proj_kernel<<<gE, blk, 0, stream>>>(
                PR, PC, edge_attr, W1, W2, b2, ei, E, cursor, recs);
        } else {
            mlp_scatter_direct_kernel<<<gE, blk, 0, stream>>>(
                x_s, x_d, edge_attr, W1, b1, W2, b2, ei, E, cursor, recs);
        }

        dim3 gC((N + 3) / 4);  // 4 nodes (waves) per block
        csr_step_kernel<<<gC, blk, 0, stream>>>(out, bufA, offsets, recs, Wf[1], N);
        csr_step_kernel<<<gC, blk, 0, stream>>>(bufA, out, offsets, recs, Wf[2], N);
    } else {
        // tier C: fused atomic path, needs only N*8 floats
        float* scattered = (float*)d_ws;
        fb_node_init_kernel<<<gN, blk, 0, stream>>>(x_d, Wf[0], out, scattered, N);
        for (int k = 0; k < 2; ++k) {
            fb_edge_step_kernel<<<gE, blk, 0, stream>>>(
                x_s, x_d, edge_attr, W1, b1, W2, b2, out, ei, E, scattered);
            fb_node_update_kernel<<<gN, blk, 0, stream>>>(out, scattered, Wf[k + 1], N);
        }
    }
}

// Round 6
// 366.567 us; speedup vs baseline: 4.0757x; 1.0543x over previous
//
#include <hip/hip_runtime.h>
#include <hip/hip_fp16.h>

#define S_FEAT 16
#define D_FEAT 8
#define E_FEAT 4
#define EDGE_IN 52   // E_FEAT + 2*S_FEAT + 2*D_FEAT
#define HIDDEN 16    // 2*D_FEAT
#define SCAN_CHUNK 2048  // elements per scan block (256 thr * 8)
#define NSUB 8           // histogram copies

typedef unsigned int uint4v __attribute__((ext_vector_type(4)));

// ---------------------------------------------------------------------------
// Full per-edge MLP (tier-B / tier-C paths)
// ---------------------------------------------------------------------------
__device__ __forceinline__ void mlp_sij(
    const float* __restrict__ x_s, const float* __restrict__ x_d,
    const float* __restrict__ edge_attr,
    const float* __restrict__ W1, const float* __restrict__ b1,
    const float* __restrict__ W2, const float* __restrict__ b2,
    int row, int col, int e, float s[D_FEAT])
{
    float in[EDGE_IN];
    {
        const float4* p = (const float4*)(x_s + (size_t)row * S_FEAT);
#pragma unroll
        for (int q = 0; q < 4; ++q) {
            float4 v = p[q];
            in[q * 4 + 0] = v.x; in[q * 4 + 1] = v.y;
            in[q * 4 + 2] = v.z; in[q * 4 + 3] = v.w;
        }
    }
    {
        const float4* p = (const float4*)(x_s + (size_t)col * S_FEAT);
#pragma unroll
        for (int q = 0; q < 4; ++q) {
            float4 v = p[q];
            in[16 + q * 4 + 0] = v.x; in[16 + q * 4 + 1] = v.y;
            in[16 + q * 4 + 2] = v.z; in[16 + q * 4 + 3] = v.w;
        }
    }
    {
        const float4* p = (const float4*)(x_d + (size_t)row * D_FEAT);
#pragma unroll
        for (int q = 0; q < 2; ++q) {
            float4 v = p[q];
            in[32 + q * 4 + 0] = v.x; in[32 + q * 4 + 1] = v.y;
            in[32 + q * 4 + 2] = v.z; in[32 + q * 4 + 3] = v.w;
        }
    }
    {
        const float4* p = (const float4*)(x_d + (size_t)col * D_FEAT);
#pragma unroll
        for (int q = 0; q < 2; ++q) {
            float4 v = p[q];
            in[40 + q * 4 + 0] = v.x; in[40 + q * 4 + 1] = v.y;
            in[40 + q * 4 + 2] = v.z; in[40 + q * 4 + 3] = v.w;
        }
    }
    {
        float4 v = *(const float4*)(edge_attr + (size_t)e * E_FEAT);
        in[48] = v.x; in[49] = v.y; in[50] = v.z; in[51] = v.w;
    }

    float h[HIDDEN];
#pragma unroll
    for (int i = 0; i < HIDDEN; ++i) {
        float acc = b1[i];
#pragma unroll
        for (int j = 0; j < EDGE_IN; ++j)
            acc = fmaf(in[j], W1[i * EDGE_IN + j], acc);
        h[i] = acc > 0.f ? acc : 0.f;
    }

    float nrm2 = 0.f;
#pragma unroll
    for (int i = 0; i < D_FEAT; ++i) {
        float acc = b2[i];
#pragma unroll
        for (int j = 0; j < HIDDEN; ++j)
            acc = fmaf(h[j], W2[i * HIDDEN + j], acc);
        s[i] = acc;
        nrm2 = fmaf(acc, acc, nrm2);
    }
    float nrm = sqrtf(nrm2);
    float inv = nrm > 0.f ? 1.f / nrm : 0.f;
#pragma unroll
    for (int i = 0; i < D_FEAT; ++i) s[i] *= inv;
}

// ---------------------------------------------------------------------------
// 16B edge record: 8 x 12-bit fixed-point s (|s|<=1) in words x,y,z; row in w.
// ---------------------------------------------------------------------------
__device__ __forceinline__ uint4v pack_rec(const float s[8], int row)
{
    int q[8];
#pragma unroll
    for (int i = 0; i < 8; ++i) {
        float v = fminf(fmaxf(s[i] * 2047.f, -2047.f), 2047.f);
        q[i] = (int)rintf(v) & 0xFFF;
    }
    uint4v r;
    r[0] = (unsigned)(q[0] | (q[1] << 12) | (q[2] << 24));
    r[1] = (unsigned)((q[2] >> 8) | (q[3] << 4) | (q[4] << 16) | (q[5] << 28));
    r[2] = (unsigned)((q[5] >> 4) | (q[6] << 8) | (q[7] << 20));
    r[3] = (unsigned)row;
    return r;
}

__device__ __forceinline__ float rec_s(uint4v r, int f)
{
    int off = f * 12;
    unsigned lo = off < 32 ? r[0] : (off < 64 ? r[1] : r[2]);
    unsigned hi = off < 32 ? r[1] : (off < 64 ? r[2] : 0u);
    unsigned sh = (unsigned)off & 31u;
    unsigned long long both = ((unsigned long long)hi << 32) | lo;
    int q = ((int)((unsigned)(both >> sh) << 20)) >> 20;   // sext 12-bit
    return (float)q * (1.f / 2047.f);
}

__device__ __forceinline__ void unpack8h(uint4v w, float* dst)
{
#pragma unroll
    for (int i = 0; i < 4; ++i) {
        unsigned u = w[i];                       // copy lane to local scalar
        __half2 h;
        h = *reinterpret_cast<__half2*>(&u);
        float2 f = __half22float2(h);
        dst[2 * i] = f.x; dst[2 * i + 1] = f.y;
    }
}

// ---------------------------------------------------------------------------
// Sort pipeline: counting sort of edges by col -> CSR
// ---------------------------------------------------------------------------
__global__ __launch_bounds__(256) void zero_counts_kernel(int* __restrict__ counts, int M)
{
    int i = blockIdx.x * blockDim.x + threadIdx.x;
    if (i < M) counts[i] = 0;
}

__global__ __launch_bounds__(256) void hist_kernel(
    const int* __restrict__ ei, int E, int N, int* __restrict__ counts8)
{
    int e = blockIdx.x * blockDim.x + threadIdx.x;
    if (e >= E) return;
    int col = ei[E + e];
    atomicAdd(&counts8[(threadIdx.x & (NSUB - 1)) * N + col], 1);
}

__global__ __launch_bounds__(256) void scan_local_kernel(
    const int* __restrict__ counts8, int* __restrict__ partial,
    int* __restrict__ blocksums, int N)
{
    __shared__ int sh[256];
    int b = blockIdx.x, t = threadIdx.x;
    int base = b * SCAN_CHUNK + t * 8;
    int v[8];
    int run = 0;
#pragma unroll
    for (int j = 0; j < 8; ++j) {
        int c = 0;
        if (base + j < N) {
#pragma unroll
            for (int s8 = 0; s8 < NSUB; ++s8)
                c += counts8[s8 * N + base + j];
        }
        v[j] = run;            // exclusive within thread
        run += c;
    }
    sh[t] = run;
    __syncthreads();
#pragma unroll
    for (int st = 1; st < 256; st <<= 1) {
        int x = (t >= st) ? sh[t - st] : 0;
        __syncthreads();
        sh[t] += x;
        __syncthreads();
    }
    int excl = sh[t] - run;    // exclusive across threads
    if (t == 255) blocksums[b] = sh[255];
#pragma unroll
    for (int j = 0; j < 8; ++j)
        if (base + j < N) partial[base + j] = excl + v[j];
}

// parallel single-wave exclusive scan over the block sums (chunks of 64)
__global__ __launch_bounds__(64) void scan_blk_kernel(int* __restrict__ bs, int NB)
{
    int lane = threadIdx.x;
    int carry = 0;
    for (int base = 0; base < NB; base += 64) {
        int i = base + lane;
        int orig = (i < NB) ? bs[i] : 0;
        int v = orig;
#pragma unroll
        for (int st = 1; st < 64; st <<= 1) {
            int t = __shfl_up(v, st);
            if (lane >= st) v += t;
        }
        if (i < NB) bs[i] = carry + v - orig;   // exclusive
        carry += __shfl(v, 63);
    }
}

__global__ __launch_bounds__(256) void scan_add_kernel(
    int* __restrict__ offsets, int* __restrict__ cursor,
    const int* __restrict__ blocksums, int N, int E)
{
    int i = blockIdx.x * blockDim.x + threadIdx.x;
    if (i < N) {
        int off = offsets[i] + blocksums[i / SCAN_CHUNK];
        offsets[i] = off;
        cursor[i]  = off;
    } else if (i == N) {
        offsets[N] = E;
    }
}

// ---------------------------------------------------------------------------
// Fused node-parallel precompute:
//   PR[n] = W1[:,0:16]@x_s + W1[:,32:40]@x_d + b1  (fp16)
//   PC[n] = W1[:,16:32]@x_s + W1[:,40:48]@x_d      (fp16)
//   out0  = x_d @ Wf0.T ;  S0[n] = rowsum(out0)
// ---------------------------------------------------------------------------
__global__ __launch_bounds__(256) void proj_init_kernel(
    const float* __restrict__ x_s, const float* __restrict__ x_d,
    const float* __restrict__ W1, const float* __restrict__ b1,
    const float* __restrict__ Wf0,
    __half* __restrict__ PRh, __half* __restrict__ PCh,
    float* __restrict__ out, float* __restrict__ S, int N)
{
    int n = blockIdx.x * blockDim.x + threadIdx.x;
    if (n >= N) return;
    float xs[S_FEAT], xd[D_FEAT];
    {
        const float4* p = (const float4*)(x_s + (size_t)n * S_FEAT);
#pragma unroll
        for (int q = 0; q < 4; ++q) {
            float4 v = p[q];
            xs[q * 4 + 0] = v.x; xs[q * 4 + 1] = v.y;
            xs[q * 4 + 2] = v.z; xs[q * 4 + 3] = v.w;
        }
        const float4* pd = (const float4*)(x_d + (size_t)n * D_FEAT);
        float4 a = pd[0], b = pd[1];
        xd[0] = a.x; xd[1] = a.y; xd[2] = a.z; xd[3] = a.w;
        xd[4] = b.x; xd[5] = b.y; xd[6] = b.z; xd[7] = b.w;
    }
    __half prh[HIDDEN], pch[HIDDEN];
#pragma unroll
    for (int i = 0; i < HIDDEN; ++i) {
        const float* w = W1 + i * EDGE_IN;
        float a = b1[i], c = 0.f;
#pragma unroll
        for (int j = 0; j < S_FEAT; ++j) {
            a = fmaf(xs[j], w[j], a);
            c = fmaf(xs[j], w[16 + j], c);
        }
#pragma unroll
        for (int j = 0; j < D_FEAT; ++j) {
            a = fmaf(xd[j], w[32 + j], a);
            c = fmaf(xd[j], w[40 + j], c);
        }
        prh[i] = __float2half_rn(a);
        pch[i] = __float2half_rn(c);
    }
    {
        uint4v* pr = (uint4v*)(PRh + (size_t)n * HIDDEN);
        uint4v* pc = (uint4v*)(PCh + (size_t)n * HIDDEN);
        pr[0] = *(uint4v*)&prh[0]; pr[1] = *(uint4v*)&prh[8];
        pc[0] = *(uint4v*)&pch[0]; pc[1] = *(uint4v*)&pch[8];
    }
    float o[D_FEAT];
    float rs = 0.f;
#pragma unroll
    for (int i = 0; i < D_FEAT; ++i) {
        float acc = 0.f;
#pragma unroll
        for (int j = 0; j < D_FEAT; ++j)
            acc = fmaf(xd[j], Wf0[i * D_FEAT + j], acc);
        o[i] = acc;
        rs += acc;
    }
    float4* op = (float4*)(out + (size_t)n * D_FEAT);
    op[0] = make_float4(o[0], o[1], o[2], o[3]);
    op[1] = make_float4(o[4], o[5], o[6], o[7]);
    S[n] = rs;
}

// ---------------------------------------------------------------------------
// Tier A edge kernel: gather fp16 PR[row], PC[col]; add edge-attr projection;
// second layer; normalize; pack; scatter to sorted position.
// ---------------------------------------------------------------------------
__global__ __launch_bounds__(256) void mlp_scatter_proj_kernel(
    const __half* __restrict__ PRh, const __half* __restrict__ PCh,
    const float* __restrict__ edge_attr,
    const float* __restrict__ W1,
    const float* __restrict__ W2, const float* __restrict__ b2,
    const int* __restrict__ ei, int E,
    int* __restrict__ cursor, uint4v* __restrict__ recs)
{
    int e = blockIdx.x * blockDim.x + threadIdx.x;
    if (e >= E) return;
    int row = ei[e], col = ei[E + e];

    float pr[HIDDEN], pc[HIDDEN];
    {
        const uint4v* p = (const uint4v*)(PRh + (size_t)row * HIDDEN);
        const uint4v* c = (const uint4v*)(PCh + (size_t)col * HIDDEN);
        uint4v p0 = p[0], p1 = p[1], c0 = c[0], c1 = c[1];
        unpack8h(p0, pr); unpack8h(p1, pr + 8);
        unpack8h(c0, pc); unpack8h(c1, pc + 8);
    }
    float4 ea = *(const float4*)(edge_attr + (size_t)e * E_FEAT);

    float h[HIDDEN];
#pragma unroll
    for (int i = 0; i < HIDDEN; ++i) {
        const float* w = W1 + i * EDGE_IN + 48;
        float acc = pr[i] + pc[i];
        acc = fmaf(ea.x, w[0], acc);
        acc = fmaf(ea.y, w[1], acc);
        acc = fmaf(ea.z, w[2], acc);
        acc = fmaf(ea.w, w[3], acc);
        h[i] = acc > 0.f ? acc : 0.f;
    }

    float s[D_FEAT];
    float nrm2 = 0.f;
#pragma unroll
    for (int i = 0; i < D_FEAT; ++i) {
        float acc = b2[i];
#pragma unroll
        for (int j = 0; j < HIDDEN; ++j)
            acc = fmaf(h[j], W2[i * HIDDEN + j], acc);
        s[i] = acc;
        nrm2 = fmaf(acc, acc, nrm2);
    }
    float nrm = sqrtf(nrm2);
    float inv = nrm > 0.f ? 1.f / nrm : 0.f;
#pragma unroll
    for (int i = 0; i < D_FEAT; ++i) s[i] *= inv;

    uint4v rec = pack_rec(s, row);
    int pos = atomicAdd(&cursor[col], 1);
    __builtin_nontemporal_store(rec, recs + pos);
}

// ---------------------------------------------------------------------------
// Tier B edge kernel (no projection tables): full MLP per edge
// ---------------------------------------------------------------------------
__global__ __launch_bounds__(256) void mlp_scatter_direct_kernel(
    const float* __restrict__ x_s, const float* __restrict__ x_d,
    const float* __restrict__ edge_attr,
    const float* __restrict__ W1, const float* __restrict__ b1,
    const float* __restrict__ W2, const float* __restrict__ b2,
    const int* __restrict__ ei, int E,
    int* __restrict__ cursor, uint4v* __restrict__ recs)
{
    int e = blockIdx.x * blockDim.x + threadIdx.x;
    if (e >= E) return;
    int row = ei[e], col = ei[E + e];
    float s[D_FEAT];
    mlp_sij(x_s, x_d, edge_attr, W1, b1, W2, b2, row, col, e, s);
    uint4v rec = pack_rec(s, row);
    int pos = atomicAdd(&cursor[col], 1);
    __builtin_nontemporal_store(rec, recs + pos);
}

// out0 + S0 only (tier B companion to proj_init)
__global__ __launch_bounds__(256) void node_init_kernel(
    const float* __restrict__ x_d, const float* __restrict__ Wf0,
    float* __restrict__ out, float* __restrict__ S, int N)
{
    int n = blockIdx.x * blockDim.x + threadIdx.x;
    if (n >= N) return;
    float xd[D_FEAT];
    const float4* p = (const float4*)(x_d + (size_t)n * D_FEAT);
    float4 a = p[0], b = p[1];
    xd[0] = a.x; xd[1] = a.y; xd[2] = a.z; xd[3] = a.w;
    xd[4] = b.x; xd[5] = b.y; xd[6] = b.z; xd[7] = b.w;
    float o[D_FEAT];
    float rs = 0.f;
#pragma unroll
    for (int i = 0; i < D_FEAT; ++i) {
        float acc = 0.f;
#pragma unroll
        for (int j = 0; j < D_FEAT; ++j)
            acc = fmaf(xd[j], Wf0[i * D_FEAT + j], acc);
        o[i] = acc;
        rs += acc;
    }
    float4* op = (float4*)(out + (size_t)n * D_FEAT);
    op[0] = make_float4(o[0], o[1], o[2], o[3]);
    op[1] = make_float4(o[4], o[5], o[6], o[7]);
    S[n] = rs;
}

// ---------------------------------------------------------------------------
// One propagation step, CSR segment-sum. Masks come from the rowsum table S:
// mask(n) = (S[n] != 0). Writes new out and new S.
// 1 wave per node; lane = (e_sub<<3) | f.
// ---------------------------------------------------------------------------
__global__ __launch_bounds__(256) void csr_step_kernel(
    const float* __restrict__ out_in, float* __restrict__ out_out,
    const float* __restrict__ S_in, float* __restrict__ S_out,
    const int* __restrict__ offsets, const uint4v* __restrict__ recs,
    const float* __restrict__ Wf, int N)
{
    int lane = threadIdx.x & 63;
    int node = blockIdx.x * 4 + (threadIdx.x >> 6);
    if (node >= N) return;
    int e_sub = lane >> 3, f = lane & 7;
    int beg = offsets[node], end = offsets[node + 1];
    float outc = out_in[(size_t)node * 8 + f];
    bool mc = (S_in[node] != 0.f);
    float acc = 0.f;
    for (int base = beg; base < end; base += 8) {
        int e = base + e_sub;
        bool valid = e < end;
        uint4v rec = (uint4v)(0u);
        if (valid) rec = __builtin_nontemporal_load(recs + e);
        int row = (int)rec[3];                 // 0 for invalid lanes (s==0 anyway)
        float s = rec_s(rec, f);
        float outr = out_in[(size_t)row * 8 + f];
        bool m = mc || (S_in[row] != 0.f);
        acc += m ? (outc - outr) * s : 0.f;
    }
    // reduce over the 8 e_sub groups (stride 8,16,32 keeps f fixed)
    acc += __shfl_xor(acc, 8);
    acc += __shfl_xor(acc, 16);
    acc += __shfl_xor(acc, 32);
    // out_new[f] = outc[f] + sum_j Wf[f][j] * acc[j]
    float upd = 0.f;
#pragma unroll
    for (int j = 0; j < 8; ++j) {
        float aj = __shfl(acc, (lane & ~7) | j);
        upd = fmaf(Wf[f * 8 + j], aj, upd);
    }
    float o = outc + upd;
    float rs = o;
    rs += __shfl_xor(rs, 1);
    rs += __shfl_xor(rs, 2);
    rs += __shfl_xor(rs, 4);
    if (e_sub == 0) {
        out_out[(size_t)node * 8 + f] = o;
        if (f == 0) S_out[node] = rs;
    }
}

// ---------------------------------------------------------------------------
// Tier C fallback (ws tiny): fused atomic kernels
// ---------------------------------------------------------------------------
__global__ __launch_bounds__(256) void fb_node_init_kernel(
    const float* __restrict__ x_d, const float* __restrict__ Wf0,
    float* __restrict__ out, float* __restrict__ scattered, int N)
{
    int n = blockIdx.x * blockDim.x + threadIdx.x;
    if (n >= N) return;
    float xd[D_FEAT];
    const float4* p = (const float4*)(x_d + (size_t)n * D_FEAT);
    float4 a = p[0], b = p[1];
    xd[0] = a.x; xd[1] = a.y; xd[2] = a.z; xd[3] = a.w;
    xd[4] = b.x; xd[5] = b.y; xd[6] = b.z; xd[7] = b.w;
    float o[D_FEAT];
#pragma unroll
    for (int i = 0; i < D_FEAT; ++i) {
        float acc = 0.f;
#pragma unroll
        for (int j = 0; j < D_FEAT; ++j)
            acc = fmaf(xd[j], Wf0[i * D_FEAT + j], acc);
        o[i] = acc;
    }
    float4* op = (float4*)(out + (size_t)n * D_FEAT);
    op[0] = make_float4(o[0], o[1], o[2], o[3]);
    op[1] = make_float4(o[4], o[5], o[6], o[7]);
    float4* sp = (float4*)(scattered + (size_t)n * D_FEAT);
    sp[0] = make_float4(0.f, 0.f, 0.f, 0.f);
    sp[1] = make_float4(0.f, 0.f, 0.f, 0.f);
}

__global__ __launch_bounds__(256) void fb_edge_step_kernel(
    const float* __restrict__ x_s, const float* __restrict__ x_d,
    const float* __restrict__ edge_attr,
    const float* __restrict__ W1, const float* __restrict__ b1,
    const float* __restrict__ W2, const float* __restrict__ b2,
    const float* __restrict__ out,
    const int* __restrict__ ei, int E, float* __restrict__ scattered)
{
    int e = blockIdx.x * blockDim.x + threadIdx.x;
    if (e >= E) return;
    int row = ei[e], col = ei[E + e];
    const float4* pr = (const float4*)(out + (size_t)row * D_FEAT);
    const float4* pc = (const float4*)(out + (size_t)col * D_FEAT);
    float4 r0 = pr[0], r1 = pr[1], c0 = pc[0], c1 = pc[1];
    float srow = r0.x + r0.y + r0.z + r0.w + r1.x + r1.y + r1.z + r1.w;
    float scol = c0.x + c0.y + c0.z + c0.w + c1.x + c1.y + c1.z + c1.w;
    if (srow == 0.f && scol == 0.f) return;
    float s[D_FEAT];
    mlp_sij(x_s, x_d, edge_attr, W1, b1, W2, b2, row, col, e, s);
    float* dst = scattered + (size_t)col * D_FEAT;
    atomicAdd(dst + 0, (c0.x - r0.x) * s[0]);
    atomicAdd(dst + 1, (c0.y - r0.y) * s[1]);
    atomicAdd(dst + 2, (c0.z - r0.z) * s[2]);
    atomicAdd(dst + 3, (c0.w - r0.w) * s[3]);
    atomicAdd(dst + 4, (c1.x - r1.x) * s[4]);
    atomicAdd(dst + 5, (c1.y - r1.y) * s[5]);
    atomicAdd(dst + 6, (c1.z - r1.z) * s[6]);
    atomicAdd(dst + 7, (c1.w - r1.w) * s[7]);
}

__global__ __launch_bounds__(256) void fb_node_update_kernel(
    float* __restrict__ out, float* __restrict__ scattered,
    const float* __restrict__ Wf, int N)
{
    int n = blockIdx.x * blockDim.x + threadIdx.x;
    if (n >= N) return;
    float sc[D_FEAT];
    float4* sp = (float4*)(scattered + (size_t)n * D_FEAT);
    float4 a = sp[0], b = sp[1];
    sc[0] = a.x; sc[1] = a.y; sc[2] = a.z; sc[3] = a.w;
    sc[4] = b.x; sc[5] = b.y; sc[6] = b.z; sc[7] = b.w;
    sp[0] = make_float4(0.f, 0.f, 0.f, 0.f);
    sp[1] = make_float4(0.f, 0.f, 0.f, 0.f);
    float4* op = (float4*)(out + (size_t)n * D_FEAT);
    float4 o0 = op[0], o1 = op[1];
    float o[D_FEAT] = {o0.x, o0.y, o0.z, o0.w, o1.x, o1.y, o1.z, o1.w};
#pragma unroll
    for (int i = 0; i < D_FEAT; ++i) {
        float acc = 0.f;
#pragma unroll
        for (int j = 0; j < D_FEAT; ++j)
            acc = fmaf(sc[j], Wf[i * D_FEAT + j], acc);
        o[i] += acc;
    }
    op[0] = make_float4(o[0], o[1], o[2], o[3]);
    op[1] = make_float4(o[4], o[5], o[6], o[7]);
}

// ---------------------------------------------------------------------------
extern "C" void kernel_launch(void* const* d_in, const int* in_sizes, int n_in,
                              void* d_out, int out_size, void* d_ws, size_t ws_size,
                              hipStream_t stream) {
    const float* x_s       = (const float*)d_in[0];
    const float* x_d       = (const float*)d_in[1];
    const float* edge_attr = (const float*)d_in[2];
    const float* W1        = (const float*)d_in[3];
    const float* b1        = (const float*)d_in[4];
    const float* W2        = (const float*)d_in[5];
    const float* b2        = (const float*)d_in[6];
    const float* Wf[3]     = {(const float*)d_in[7], (const float*)d_in[8],
                              (const float*)d_in[9]};
    const int*   ei        = (const int*)d_in[10];

    const int N = in_sizes[1] / D_FEAT;
    const int E = in_sizes[10] / 2;

    float* out = (float*)d_out;

    // ---- workspace layout ----
    size_t off = 0;
    auto carve = [&](size_t bytes) { size_t p = off; off = (off + bytes + 255) & ~255ULL; return p; };
    size_t o_counts  = carve((size_t)NSUB * N * 4);
    size_t o_offsets = carve((size_t)(N + 1) * 4);
    size_t o_cursor  = carve((size_t)(N + 1) * 4);
    size_t o_bsums   = carve(256 * 4);
    size_t o_bufA    = carve((size_t)N * D_FEAT * 4);
    size_t o_SA      = carve((size_t)N * 4);
    size_t o_SB      = carve((size_t)N * 4);
    size_t o_recs    = carve((size_t)E * 16);
    const size_t need_base = off;                       // tier B
    size_t o_PR      = carve((size_t)N * HIDDEN * 2);   // fp16
    size_t o_PC      = carve((size_t)N * HIDDEN * 2);   // fp16
    const size_t need_full = off;                       // tier A

    dim3 blk(256);
    dim3 gE((E + 255) / 256);
    dim3 gN((N + 255) / 256);

    if (ws_size >= need_base) {
        char* ws = (char*)d_ws;
        int*   counts8 = (int*)(ws + o_counts);
        int*   offsets = (int*)(ws + o_offsets);
        int*   cursor  = (int*)(ws + o_cursor);
        int*   bsums   = (int*)(ws + o_bsums);
        float* bufA    = (float*)(ws + o_bufA);
        float* SA      = (float*)(ws + o_SA);
        float* SB      = (float*)(ws + o_SB);
        uint4v* recs   = (uint4v*)(ws + o_recs);

        const int NB = (N + SCAN_CHUNK - 1) / SCAN_CHUNK;

        zero_counts_kernel<<<dim3((NSUB * N + 255) / 256), blk, 0, stream>>>(counts8, NSUB * N);
        hist_kernel<<<gE, blk, 0, stream>>>(ei, E, N, counts8);
        scan_local_kernel<<<dim3(NB), blk, 0, stream>>>(counts8, offsets, bsums, N);
        scan_blk_kernel<<<dim3(1), dim3(64), 0, stream>>>(bsums, NB);
        scan_add_kernel<<<dim3((N + 256) / 256), blk, 0, stream>>>(offsets, cursor, bsums, N, E);

        if (ws_size >= need_full) {
            __half* PRh = (__half*)(ws + o_PR);
            __half* PCh = (__half*)(ws + o_PC);
            proj_init_kernel<<<gN, blk, 0, stream>>>(
                x_s, x_d, W1, b1, Wf[0], PRh, PCh, out, SA, N);
            mlp_scatter_proj_kernel<<<gE, blk, 0, stream>>>(
                PRh, PCh, edge_attr, W1, W2, b2, ei, E, cursor, recs);
        } else {
            node_init_kernel<<<gN, blk, 0, stream>>>(x_d, Wf[0], out, SA, N);
            mlp_scatter_direct_kernel<<<gE, blk, 0, stream>>>(
                x_s, x_d, edge_attr, W1, b1, W2, b2, ei, E, cursor, recs);
        }

        dim3 gC((N + 3) / 4);  // 4 nodes (waves) per block
        csr_step_kernel<<<gC, blk, 0, stream>>>(out, bufA, SA, SB, offsets, recs, Wf[1], N);
        csr_step_kernel<<<gC, blk, 0, stream>>>(bufA, out, SB, SA, offsets, recs, Wf[2], N);
    } else {
        // tier C: fused atomic path, needs only N*8 floats
        float* scattered = (float*)d_ws;
        fb_node_init_kernel<<<gN, blk, 0, stream>>>(x_d, Wf[0], out, scattered, N);
        for (int k = 0; k < 2; ++k) {
            fb_edge_step_kernel<<<gE, blk, 0, stream>>>(
                x_s, x_d, edge_attr, W1, b1, W2, b2, out, ei, E, scattered);
            fb_node_update_kernel<<<gN, blk, 0, stream>>>(out, scattered, Wf[k + 1], N);
        }
    }
}